// Round 11
// baseline (495.171 us; speedup 1.0000x reference)
//
#include <hip/hip_runtime.h>
#include <math.h>

typedef __bf16 bf16x8 __attribute__((ext_vector_type(8)));
typedef float f32x4 __attribute__((ext_vector_type(4)));

// ---------------- bf16 helpers ----------------
__device__ __forceinline__ unsigned short f2bf(float f) {
    unsigned u = __float_as_uint(f);
    return (unsigned short)((u + 0x7fffu + ((u >> 16) & 1u)) >> 16);
}
__device__ __forceinline__ float2 bf2(unsigned u) {
    float2 r;
    r.x = __uint_as_float(u << 16);
    r.y = __uint_as_float(u & 0xffff0000u);
    return r;
}

// ---------------- prep: x -> bf16 ----------------
__global__ __launch_bounds__(256) void convert_x(
    const float* __restrict__ x, unsigned short* __restrict__ xb, int total)
{
    int g = blockIdx.x * blockDim.x + threadIdx.x;
    if (g < total) xb[g] = f2bf(x[g]);
}

// ---------------- prep: 640-col transposed bf16 weights + folded bias ----------------
// Output-column order == final P position (kv interleave baked in):
//   p in [0,256): cc = 2*(p>>2)+(p&1), W = (p&2)?Wv:Wk, +be folded.
//   [256,384)=q (Wq,bq); [384,512)=s (Ws,bs);
//   [512,640): qWe fused cols: Wt[c][d] = sum_i Wq[d,h*C+i]*We[kk*128+h*C+i].
__global__ __launch_bounds__(256) void prep_w(
    const float* __restrict__ Wq, const float* __restrict__ bq,
    const float* __restrict__ Wk, const float* __restrict__ bk,
    const float* __restrict__ Wv, const float* __restrict__ bv,
    const float* __restrict__ be,
    const float* __restrict__ Ws, const float* __restrict__ bs,
    const float* __restrict__ We, int H,
    unsigned short* __restrict__ Wt, float* __restrict__ bias)
{
    int g = blockIdx.x * blockDim.x + threadIdx.x;
    const int C = 128 / H;
    if (g < 640) {
        int p = g;
        float b;
        if (p < 256) {
            int cc = 2 * (p >> 2) + (p & 1);
            b = ((p & 2) ? bv[cc] : bk[cc]) + be[cc];
        }
        else if (p < 384) b = bq[p - 256];
        else if (p < 512) b = bs[p - 384];
        else {
            int c2 = p - 512, h = c2 >> 4, kk = c2 & 15;
            b = 0.f;
            if (h < H) for (int i = 0; i < C; ++i) b += bq[h * C + i] * We[kk * 128 + h * C + i];
        }
        bias[p] = b;
    }
    if (g >= 640 * 128) return;
    int p = g >> 7, d = g & 127;
    float w;
    if (p < 256) {
        int cc = 2 * (p >> 2) + (p & 1);
        w = (p & 2) ? Wv[d * 128 + cc] : Wk[d * 128 + cc];
    } else if (p < 384) {
        w = Wq[d * 128 + (p - 256)];
    } else if (p < 512) {
        w = Ws[d * 128 + (p - 384)];
    } else {
        int c2 = p - 512, h = c2 >> 4, kk = c2 & 15;
        w = 0.f;
        if (h < H) for (int i = 0; i < C; ++i) w += Wq[d * 128 + h * C + i] * We[kk * 128 + h * C + i];
    }
    Wt[(size_t)p * 128 + d] = f2bf(w);
}

// ---------------- MFMA bf16 GEMM: [P | qWe] = Xb[m,128] @ Wt + bias ----------------
// Round-0 structure (2D grid). B tile (64 cols x 128 k, 16 KB) staged in
// LDS. C-frag: col=lane&15, row=(lane>>4)*4+reg [m89/m91]. Epilogue via
// LDS for coalesced stores.
__global__ __launch_bounds__(256) void gemm_bf16(
    const unsigned short* __restrict__ Xb, int M,
    const unsigned short* __restrict__ Wt, const float* __restrict__ bias,
    unsigned short* __restrict__ P, float* __restrict__ qWe)
{
    __shared__ unsigned short Bs[64][136];
    __shared__ unsigned short tile[4][16][64];
    const int wv = threadIdx.x >> 6, lane = threadIdx.x & 63;
    const int row0 = blockIdx.x * 64 + wv * 16;
    const int n0 = blockIdx.y * 64;                 // [0,640)
    const int quad = lane >> 4, l16 = lane & 15;

    {   // stage Wt column-tile into LDS: 1024 x uint4, coalesced
        const uint4* gsrc = (const uint4*)(Wt + (size_t)n0 * 128);
#pragma unroll
        for (int u = 0; u < 4; ++u) {
            int v = threadIdx.x + u * 256;
            int col = v >> 4, k8 = v & 15;
            *(uint4*)(&Bs[col][k8 * 8]) = gsrc[v];
        }
    }
    __syncthreads();

    f32x4 acc[4] = {};
    int mrow = row0 + l16; if (mrow >= M) mrow = M - 1;  // clamp loads; stores guarded
    const int kb = quad * 8;
#pragma unroll
    for (int kk = 0; kk < 4; ++kk) {
        bf16x8 a = *(const bf16x8*)(Xb + (size_t)mrow * 128 + kk * 32 + kb);
#pragma unroll
        for (int f = 0; f < 4; ++f) {
            bf16x8 b = *(const bf16x8*)(&Bs[f * 16 + l16][kk * 32 + kb]);
            acc[f] = __builtin_amdgcn_mfma_f32_16x16x32_bf16(a, b, acc[f], 0, 0, 0);
        }
    }
    if (n0 < 512) {
#pragma unroll
        for (int f = 0; f < 4; ++f) {
            float bs = bias[n0 + f * 16 + l16];
#pragma unroll
            for (int r = 0; r < 4; ++r) {
                int row = quad * 4 + r;
                int col = f * 16 + l16;
                tile[wv][row][col ^ ((row & 3) << 4)] = f2bf(acc[f][r] + bs);
            }
        }
        __syncthreads();
        int row = lane >> 2, seg = lane & 3;
        int m = row0 + row;
        if (m < M) {
            const uint4* src = (const uint4*)&tile[wv][row][(seg ^ (row & 3)) << 4];
            uint4* dst = (uint4*)(P + (size_t)m * 512 + n0 + seg * 16);
            dst[0] = src[0];
            dst[1] = src[1];
        }
    } else {
#pragma unroll
        for (int f = 0; f < 4; ++f) {
            int c = n0 + f * 16 + l16;
            float bs = bias[c];
#pragma unroll
            for (int r = 0; r < 4; ++r) {
                int m = row0 + quad * 4 + r;
                if (m < M) qWe[(size_t)m * 128 + (c - 512)] = acc[f][r] + bs;
            }
        }
    }
}

// ---------------- CSR build (int atomics only) ----------------
__global__ __launch_bounds__(256) void degree_kernel(
    const int* __restrict__ ei, int* __restrict__ deg, int E)
{
    int e = blockIdx.x * blockDim.x + threadIdx.x;
    if (e < E) atomicAdd(&deg[ei[E + e]], 1);
}

// Block-parallel 3-phase prefix sum (r9 win: replaced 122us single-block scan).
__global__ __launch_bounds__(256) void scan_part1(
    const int* __restrict__ deg, int* __restrict__ partial, int N)
{
    __shared__ int s[256];
    const int t = threadIdx.x;
    const int g = blockIdx.x * 256 + t;
    int v = (g < N) ? deg[g] : 0;
    s[t] = v;
    __syncthreads();
    for (int ofs = 128; ofs > 0; ofs >>= 1) {
        if (t < ofs) s[t] += s[t + ofs];
        __syncthreads();
    }
    if (t == 0) partial[blockIdx.x] = s[0];
}

__global__ __launch_bounds__(256) void scan_part2(
    int* __restrict__ partial)   // 256 entries -> exclusive offsets in-place
{
    __shared__ int s[256];
    const int t = threadIdx.x;
    int v = partial[t];
    s[t] = v;
    __syncthreads();
    for (int ofs = 1; ofs < 256; ofs <<= 1) {
        int u = (t >= ofs) ? s[t - ofs] : 0;
        __syncthreads();
        s[t] += u;
        __syncthreads();
    }
    partial[t] = s[t] - v;   // exclusive
}

__global__ __launch_bounds__(256) void scan_part3(
    const int* __restrict__ deg, const int* __restrict__ offs,
    int* __restrict__ rowptr, int* __restrict__ cursor, int N)
{
    __shared__ int s[256];
    const int t = threadIdx.x;
    const int g = blockIdx.x * 256 + t;
    int v = (g < N) ? deg[g] : 0;
    s[t] = v;
    __syncthreads();
    for (int ofs = 1; ofs < 256; ofs <<= 1) {
        int u = (t >= ofs) ? s[t - ofs] : 0;
        __syncthreads();
        s[t] += u;
        __syncthreads();
    }
    const int incl = s[t];
    const int base = offs[blockIdx.x];
    if (g < N) {
        cursor[g] = base + incl - v;      // exclusive prefix
        rowptr[g + 1] = base + incl;      // inclusive prefix
    }
    if (g == 0) rowptr[0] = 0;
}

__global__ __launch_bounds__(256) void scatter_kernel(
    const int* __restrict__ ei, int* __restrict__ cursor,
    int2* __restrict__ csr, int E)
{
    int e = blockIdx.x * blockDim.x + threadIdx.x;
    if (e < E) {
        int pos = atomicAdd(&cursor[ei[E + e]], 1);
        csr[pos] = make_int2(ei[e], e);   // (src, edge id)
    }
}

// ---------------- fused score + online-softmax + aggregation ----------------
// ROUND 11: quarter-wave (r10 win) + CHUNK=8. Wave-rate ledger (362->248->139
// w/us as waves fattened) shows wave supply is no longer binding; per-wave
// serial time is (15 us lifetime). Chunk 4->8 halves serial softmax rounds
// per node (~5 -> ~3 at max-deg ~18 over 4 quarters) and doubles loads in
// flight (16->32). Wave count unchanged (12500). Buffer VGPRs double
// (~64->~128, total ~140; occupancy cap 12/CU > achieved 8/CU).
// SPILL CANARY: fused1 WRITE_SIZE must stay 12.5 MB.
__global__ __launch_bounds__(256) void fused1_node(
    const unsigned short* __restrict__ P, const float* __restrict__ qWe,
    const float* __restrict__ ea, const float* __restrict__ We1,
    const int2* __restrict__ csr, const int* __restrict__ rowptr,
    unsigned short* __restrict__ h1, int N)
{
    const int lane = threadIdx.x & 63;
    const int node = blockIdx.x * 16 + (threadIdx.x >> 4);   // one node per quarter
    if (node >= N) return;
    const int l16 = lane & 15;
    const int qbit = lane & 48;       // quarter base (shfl indices)
    const int pbit = lane & 62;       // head-pair base (2 lanes per head)
    const int odd  = lane & 1;        // which ea-feature half this lane owns
    const int c0 = l16 * 8;           // 8 channels per lane

    const int beg = rowptr[node];
    const int deg = rowptr[node + 1] - beg;

    uint4 su = *(const uint4*)(P + (size_t)node * 512 + 384 + c0);
    float2 sk0 = bf2(su.x), sk1 = bf2(su.y), sk2 = bf2(su.z), sk3 = bf2(su.w);
    if (deg == 0) {
        float o0 = sk0.x > 0.f ? sk0.x : 0.01f * sk0.x;
        float o1 = sk0.y > 0.f ? sk0.y : 0.01f * sk0.y;
        float o2 = sk1.x > 0.f ? sk1.x : 0.01f * sk1.x;
        float o3 = sk1.y > 0.f ? sk1.y : 0.01f * sk1.y;
        float o4 = sk2.x > 0.f ? sk2.x : 0.01f * sk2.x;
        float o5 = sk2.y > 0.f ? sk2.y : 0.01f * sk2.y;
        float o6 = sk3.x > 0.f ? sk3.x : 0.01f * sk3.x;
        float o7 = sk3.y > 0.f ? sk3.y : 0.01f * sk3.y;
        uint4 pk;
        pk.x = (unsigned)f2bf(o0) | ((unsigned)f2bf(o1) << 16);
        pk.y = (unsigned)f2bf(o2) | ((unsigned)f2bf(o3) << 16);
        pk.z = (unsigned)f2bf(o4) | ((unsigned)f2bf(o5) << 16);
        pk.w = (unsigned)f2bf(o6) | ((unsigned)f2bf(o7) << 16);
        *(uint4*)(h1 + (size_t)node * 128 + c0) = pk;
        return;
    }

    uint4 qu = *(const uint4*)(P + (size_t)node * 512 + 256 + c0);
    float2 q0 = bf2(qu.x), q1 = bf2(qu.y), q2 = bf2(qu.z), q3 = bf2(qu.w);
    float4 qwA = *(const float4*)(qWe + (size_t)node * 128 + c0);
    float4 qwB = *(const float4*)(qWe + (size_t)node * 128 + c0 + 4);

    float4 acA = make_float4(0.f, 0.f, 0.f, 0.f);   // v accum ch c0..c0+3
    float4 acB = make_float4(0.f, 0.f, 0.f, 0.f);   // v accum ch c0+4..+7
    float4 A2a = make_float4(0.f, 0.f, 0.f, 0.f);   // ea accum kk odd*8..+3
    float4 A2b = make_float4(0.f, 0.f, 0.f, 0.f);   // ea accum kk odd*8+4..+7
    float m = -INFINITY, lden = 0.f;

    int2 se = make_int2(0, 0);
    if (l16 < deg) se = csr[beg + l16];

    for (int blk = 0; blk < deg; blk += 16) {
        if (blk) se = (blk + l16 < deg) ? csr[beg + blk + l16] : make_int2(0, 0);
        const int bcnt = min(16, deg - blk);
        for (int cb = 0; cb < bcnt; cb += 8) {
            const int lim = min(8, bcnt - cb);
            uint4 kva[8], kvb[8]; float4 eaA[8], eaB[8];
            // ---- gather phase: loads only (up to 32 in flight) ----
#pragma unroll
            for (int i = 0; i < 8; ++i) {
                if (i < lim) {   // quarter-uniform
                    int jc = min(cb + i, bcnt - 1);
                    int sb = __shfl(se.x, qbit | jc, 64);
                    int eb = __shfl(se.y, qbit | jc, 64);
                    const unsigned short* kp = P + (size_t)sb * 512 + l16 * 16;
                    kva[i] = *(const uint4*)(kp);
                    kvb[i] = *(const uint4*)(kp + 8);
                    const float* ep = ea + (size_t)eb * 16 + odd * 8;
                    eaA[i] = *(const float4*)(ep);
                    eaB[i] = *(const float4*)(ep + 4);
                }
            }
            // ---- score phase: owner lane odd==(i&1), slot i>>1 ----
            float s0 = -INFINITY, s1 = -INFINITY, s2 = -INFINITY, s3 = -INFINITY;
#pragma unroll
            for (int i = 0; i < 8; ++i) {
                if (i < lim) {
                    float2 ka = bf2(kva[i].x), kb = bf2(kva[i].z);
                    float2 kc = bf2(kvb[i].x), kd = bf2(kvb[i].z);
                    float p = q0.x * ka.x + q0.y * ka.y + q1.x * kb.x + q1.y * kb.y
                            + q2.x * kc.x + q2.y * kc.y + q3.x * kd.x + q3.y * kd.y
                            + qwA.x * eaA[i].x + qwA.y * eaA[i].y
                            + qwA.z * eaA[i].z + qwA.w * eaA[i].w
                            + qwB.x * eaB[i].x + qwB.y * eaB[i].y
                            + qwB.z * eaB[i].z + qwB.w * eaB[i].w;
                    p += __shfl_xor(p, 1, 64);    // head-pair sum
                    float pv = p * 0.25f;         // 1/sqrt(16)
                    if (odd == (i & 1)) {
                        if ((i >> 1) == 0) s0 = pv;
                        else if ((i >> 1) == 1) s1 = pv;
                        else if ((i >> 1) == 2) s2 = pv;
                        else s3 = pv;
                    }
                }
            }
            // ---- online softmax update (per head; pair-local) ----
            float cm = fmaxf(fmaxf(s0, s1), fmaxf(s2, s3));
            cm = fmaxf(cm, __shfl_xor(cm, 1, 64));
            float m_new = fmaxf(m, cm);
            float scale = __expf(m - m_new);      // first chunk: exp(-inf)=0
            float e0 = __expf(s0 - m_new);        // unassigned slots: 0
            float e1 = __expf(s1 - m_new);
            float e2 = __expf(s2 - m_new);
            float e3 = __expf(s3 - m_new);
            float ds = (e0 + e1) + (e2 + e3);
            ds += __shfl_xor(ds, 1, 64);
            lden = lden * scale + ds;
            acA.x *= scale; acA.y *= scale; acA.z *= scale; acA.w *= scale;
            acB.x *= scale; acB.y *= scale; acB.z *= scale; acB.w *= scale;
            A2a.x *= scale; A2a.y *= scale; A2a.z *= scale; A2a.w *= scale;
            A2b.x *= scale; A2b.y *= scale; A2b.z *= scale; A2b.w *= scale;
            m = m_new;
            // ---- accumulate phase ----
#pragma unroll
            for (int i = 0; i < 8; ++i) {
                if (i < lim) {
                    float esel = (i >> 1) == 0 ? e0 : (i >> 1) == 1 ? e1 :
                                 (i >> 1) == 2 ? e2 : e3;
                    float w = __shfl(esel, pbit | (i & 1), 64);
                    float2 va = bf2(kva[i].y), vb = bf2(kva[i].w);
                    float2 vc = bf2(kvb[i].y), vd = bf2(kvb[i].w);
                    acA.x += w * va.x; acA.y += w * va.y;
                    acA.z += w * vb.x; acA.w += w * vb.y;
                    acB.x += w * vc.x; acB.y += w * vc.y;
                    acB.z += w * vd.x; acB.w += w * vd.y;
                    A2a.x += w * eaA[i].x; A2a.y += w * eaA[i].y;
                    A2a.z += w * eaA[i].z; A2a.w += w * eaA[i].w;
                    A2b.x += w * eaB[i].x; A2b.y += w * eaB[i].y;
                    A2b.z += w * eaB[i].z; A2b.w += w * eaB[i].w;
                }
            }
        }
    }

    // expand A_h through We1 (pair-local). Lane pbit|(k>>3) holds feature k
    // (component k&7 of its A2a/A2b).
    float ex0 = 0.f, ex1 = 0.f, ex2 = 0.f, ex3 = 0.f;
    float ex4 = 0.f, ex5 = 0.f, ex6 = 0.f, ex7 = 0.f;
#pragma unroll
    for (int k = 0; k < 16; ++k) {
        float comp = (k & 7) == 0 ? A2a.x : (k & 7) == 1 ? A2a.y :
                     (k & 7) == 2 ? A2a.z : (k & 7) == 3 ? A2a.w :
                     (k & 7) == 4 ? A2b.x : (k & 7) == 5 ? A2b.y :
                     (k & 7) == 6 ? A2b.z : A2b.w;
        float ak = __shfl(comp, pbit | (k >> 3), 64);
        const float* wp = We1 + k * 128 + c0;
        float4 w4a = *(const float4*)(wp);
        float4 w4b = *(const float4*)(wp + 4);
        ex0 += ak * w4a.x; ex1 += ak * w4a.y; ex2 += ak * w4a.z; ex3 += ak * w4a.w;
        ex4 += ak * w4b.x; ex5 += ak * w4b.y; ex6 += ak * w4b.z; ex7 += ak * w4b.w;
    }
    float inv = 1.f / (lden + 1e-16f);
    float o0 = (acA.x + ex0) * inv + sk0.x;
    float o1 = (acA.y + ex1) * inv + sk0.y;
    float o2 = (acA.z + ex2) * inv + sk1.x;
    float o3 = (acA.w + ex3) * inv + sk1.y;
    float o4 = (acB.x + ex4) * inv + sk2.x;
    float o5 = (acB.y + ex5) * inv + sk2.y;
    float o6 = (acB.z + ex6) * inv + sk3.x;
    float o7 = (acB.w + ex7) * inv + sk3.y;
    o0 = o0 > 0.f ? o0 : 0.01f * o0;
    o1 = o1 > 0.f ? o1 : 0.01f * o1;
    o2 = o2 > 0.f ? o2 : 0.01f * o2;
    o3 = o3 > 0.f ? o3 : 0.01f * o3;
    o4 = o4 > 0.f ? o4 : 0.01f * o4;
    o5 = o5 > 0.f ? o5 : 0.01f * o5;
    o6 = o6 > 0.f ? o6 : 0.01f * o6;
    o7 = o7 > 0.f ? o7 : 0.01f * o7;
    uint4 pk;
    pk.x = (unsigned)f2bf(o0) | ((unsigned)f2bf(o1) << 16);
    pk.y = (unsigned)f2bf(o2) | ((unsigned)f2bf(o3) << 16);
    pk.z = (unsigned)f2bf(o4) | ((unsigned)f2bf(o5) << 16);
    pk.w = (unsigned)f2bf(o6) | ((unsigned)f2bf(o7) << 16);
    *(uint4*)(h1 + (size_t)node * 128 + c0) = pk;
}

// Layer 2: H=1, C=128. One node per 16-lane quarter; 16-lane dot per edge
// (4 shfl_xor); lanes 0..7 of the quarter hold the chunk's scores (chunk=8).
__global__ __launch_bounds__(256) void fused2_node(
    const unsigned short* __restrict__ P, const float* __restrict__ qWe,
    const float* __restrict__ ea, const float* __restrict__ We2,
    const int2* __restrict__ csr, const int* __restrict__ rowptr,
    float* __restrict__ out, int N)
{
    const int lane = threadIdx.x & 63;
    const int node = blockIdx.x * 16 + (threadIdx.x >> 4);
    if (node >= N) return;
    const int l16 = lane & 15;
    const int qbit = lane & 48;
    const int c0 = l16 * 8;

    const int beg = rowptr[node];
    const int deg = rowptr[node + 1] - beg;

    uint4 su = *(const uint4*)(P + (size_t)node * 512 + 384 + c0);
    float2 sk0 = bf2(su.x), sk1 = bf2(su.y), sk2 = bf2(su.z), sk3 = bf2(su.w);
    float* outp = out + (size_t)node * 128 + c0;
    if (deg == 0) {
        *(float4*)outp = make_float4(sk0.x, sk0.y, sk1.x, sk1.y);
        *(float4*)(outp + 4) = make_float4(sk2.x, sk2.y, sk3.x, sk3.y);
        return;
    }

    uint4 qu = *(const uint4*)(P + (size_t)node * 512 + 256 + c0);
    float2 q0 = bf2(qu.x), q1 = bf2(qu.y), q2 = bf2(qu.z), q3 = bf2(qu.w);
    float qw = qWe[(size_t)node * 128 + l16];

    float4 acA = make_float4(0.f, 0.f, 0.f, 0.f);
    float4 acB = make_float4(0.f, 0.f, 0.f, 0.f);
    float accA = 0.f;
    float m = -INFINITY, lden = 0.f;

    int2 se = make_int2(0, 0);
    if (l16 < deg) se = csr[beg + l16];

    for (int blk = 0; blk < deg; blk += 16) {
        if (blk) se = (blk + l16 < deg) ? csr[beg + blk + l16] : make_int2(0, 0);
        const int bcnt = min(16, deg - blk);
        for (int cb = 0; cb < bcnt; cb += 8) {
            const int lim = min(8, bcnt - cb);
            uint4 kva[8], kvb[8]; float eav[8];
            // ---- gather phase ----
#pragma unroll
            for (int i = 0; i < 8; ++i) {
                if (i < lim) {
                    int jc = min(cb + i, bcnt - 1);
                    int sb = __shfl(se.x, qbit | jc, 64);
                    int eb = __shfl(se.y, qbit | jc, 64);
                    const unsigned short* kp = P + (size_t)sb * 512 + l16 * 16;
                    kva[i] = *(const uint4*)(kp);
                    kvb[i] = *(const uint4*)(kp + 8);
                    eav[i] = ea[(size_t)eb * 16 + l16];
                }
            }
            // ---- score phase (16-lane dot within quarter) ----
            float my_s = -INFINITY;
#pragma unroll
            for (int i = 0; i < 8; ++i) {
                if (i < lim) {
                    float2 ka = bf2(kva[i].x), kb = bf2(kva[i].z);
                    float2 kc = bf2(kvb[i].x), kd = bf2(kvb[i].z);
                    float p = q0.x * ka.x + q0.y * ka.y + q1.x * kb.x + q1.y * kb.y
                            + q2.x * kc.x + q2.y * kc.y + q3.x * kd.x + q3.y * kd.y
                            + qw * eav[i];
                    p += __shfl_xor(p, 1, 64);
                    p += __shfl_xor(p, 2, 64);
                    p += __shfl_xor(p, 4, 64);
                    p += __shfl_xor(p, 8, 64);     // quarter-wide reduction
                    if (l16 == i) my_s = p * 0.08838834764831845f;  // 1/sqrt(128)
                }
            }
            // ---- online softmax (quarter-local) ----
            float cm = my_s;
#pragma unroll
            for (int mk = 1; mk < 16; mk <<= 1) cm = fmaxf(cm, __shfl_xor(cm, mk, 64));
            float m_new = fmaxf(m, cm);
            float scale = __expf(m - m_new);
            float ew = __expf(my_s - m_new);   // non-slot: 0
            float ds = ew;
#pragma unroll
            for (int mk = 1; mk < 16; mk <<= 1) ds += __shfl_xor(ds, mk, 64);
            lden = lden * scale + ds;
            acA.x *= scale; acA.y *= scale; acA.z *= scale; acA.w *= scale;
            acB.x *= scale; acB.y *= scale; acB.z *= scale; acB.w *= scale;
            accA *= scale;
            m = m_new;
            // ---- accumulate ----
#pragma unroll
            for (int i = 0; i < 8; ++i) {
                if (i < lim) {
                    float w = __shfl(ew, qbit | i, 64);
                    float2 va = bf2(kva[i].y), vb = bf2(kva[i].w);
                    float2 vc = bf2(kvb[i].y), vd = bf2(kvb[i].w);
                    acA.x += w * va.x; acA.y += w * va.y;
                    acA.z += w * vb.x; acA.w += w * vb.y;
                    acB.x += w * vc.x; acB.y += w * vc.y;
                    acB.z += w * vd.x; acB.w += w * vd.y;
                    accA += w * eav[i];
                }
            }
        }
    }

    float ex0 = 0.f, ex1 = 0.f, ex2 = 0.f, ex3 = 0.f;
    float ex4 = 0.f, ex5 = 0.f, ex6 = 0.f, ex7 = 0.f;
#pragma unroll
    for (int k = 0; k < 16; ++k) {
        float ak = __shfl(accA, qbit | k, 64);   // lane qbit+k holds feature k
        const float* wp = We2 + k * 128 + c0;
        float4 w4a = *(const float4*)(wp);
        float4 w4b = *(const float4*)(wp + 4);
        ex0 += ak * w4a.x; ex1 += ak * w4a.y; ex2 += ak * w4a.z; ex3 += ak * w4a.w;
        ex4 += ak * w4b.x; ex5 += ak * w4b.y; ex6 += ak * w4b.z; ex7 += ak * w4b.w;
    }
    float inv = 1.f / (lden + 1e-16f);
    float4 oA, oB;
    oA.x = (acA.x + ex0) * inv + sk0.x;
    oA.y = (acA.y + ex1) * inv + sk0.y;
    oA.z = (acA.z + ex2) * inv + sk1.x;
    oA.w = (acA.w + ex3) * inv + sk1.y;
    oB.x = (acB.x + ex4) * inv + sk2.x;
    oB.y = (acB.y + ex5) * inv + sk2.y;
    oB.z = (acB.z + ex6) * inv + sk3.x;
    oB.w = (acB.w + ex7) * inv + sk3.y;
    *(float4*)outp = oA;
    *(float4*)(outp + 4) = oB;
}

// ---------------- launch ----------------
extern "C" void kernel_launch(void* const* d_in, const int* in_sizes, int n_in,
                              void* d_out, int out_size, void* d_ws, size_t ws_size,
                              hipStream_t stream)
{
    const float* x  = (const float*)d_in[0];
    const int*   ei = (const int*)d_in[1];
    const float* ea = (const float*)d_in[2];
    const float *Wq1 = (const float*)d_in[3],  *bq1 = (const float*)d_in[4];
    const float *Wk1 = (const float*)d_in[5],  *bk1 = (const float*)d_in[6];
    const float *Wv1 = (const float*)d_in[7],  *bv1 = (const float*)d_in[8];
    const float *We1 = (const float*)d_in[9],  *be1 = (const float*)d_in[10];
    const float *Ws1 = (const float*)d_in[11], *bs1 = (const float*)d_in[12];
    const float *Wq2 = (const float*)d_in[13], *bq2 = (const float*)d_in[14];
    const float *Wk2 = (const float*)d_in[15], *bk2 = (const float*)d_in[16];
    const float *Wv2 = (const float*)d_in[17], *bv2 = (const float*)d_in[18];
    const float *We2 = (const float*)d_in[19], *be2 = (const float*)d_in[20];
    const float *Ws2 = (const float*)d_in[21], *bs2 = (const float*)d_in[22];

    const int N = in_sizes[0] / 128;
    const int E = in_sizes[1] / 2;

    char* ws = (char*)d_ws;
    size_t off = 0;
    auto alloc = [&](size_t bytes) -> void* {
        void* p = ws + off;
        off = (off + bytes + 255) & ~(size_t)255;
        return p;
    };
    unsigned short* xb  = (unsigned short*)alloc((size_t)N * 128 * 2);
    unsigned short* P   = (unsigned short*)alloc((size_t)N * 512 * 2);  // bf16 [kv-interleave | q | s]
    unsigned short* h1b = (unsigned short*)alloc((size_t)N * 128 * 2);
    unsigned short* Wt1 = (unsigned short*)alloc((size_t)640 * 128 * 2);
    unsigned short* Wt2 = (unsigned short*)alloc((size_t)640 * 128 * 2);
    float* bias1 = (float*)alloc(640 * 4);
    float* bias2 = (float*)alloc(640 * 4);
    float* qWe   = (float*)alloc((size_t)N * 128 * 4);
    int*  deg    = (int*)alloc((size_t)N * 4);
    int*  rowptr = (int*)alloc((size_t)(N + 1) * 4);
    int*  cursor = (int*)alloc((size_t)N * 4);
    int*  partial= (int*)alloc(256 * 4);
    int2* csr    = (int2*)alloc((size_t)E * 8);

    dim3 gemm_grid1((N + 63) / 64, 10);
    dim3 gemm_grid2((N + 63) / 64, 9);   // layer-2 qWe needs only cols [512,528)
    const int tn = N * 128;
    const int node_blocks = (N + 15) / 16;   // 16 nodes (16 quarter-waves) per 256-thread block
    const int prep_blocks = (640 * 128 + 255) / 256;
    const int scan_blocks = (N + 255) / 256; // <=256 required (N<=65536)

    // ---- prep (independent of everything else) ----
    convert_x<<<(tn + 255) / 256, 256, 0, stream>>>(x, xb, tn);
    prep_w<<<prep_blocks, 256, 0, stream>>>(Wq1, bq1, Wk1, bk1, Wv1, bv1, be1, Ws1, bs1, We1, 8, Wt1, bias1);
    prep_w<<<prep_blocks, 256, 0, stream>>>(Wq2, bq2, Wk2, bk2, Wv2, bv2, be2, Ws2, bs2, We2, 1, Wt2, bias2);

    // ---- CSR build (shared by both layers) ----
    hipMemsetAsync(deg, 0, (size_t)N * 4, stream);
    hipMemsetAsync(partial, 0, 256 * 4, stream);
    degree_kernel<<<(E + 255) / 256, 256, 0, stream>>>(ei, deg, E);
    scan_part1<<<scan_blocks, 256, 0, stream>>>(deg, partial, N);
    scan_part2<<<1, 256, 0, stream>>>(partial);
    scan_part3<<<scan_blocks, 256, 0, stream>>>(deg, partial, rowptr, cursor, N);
    scatter_kernel<<<(E + 255) / 256, 256, 0, stream>>>(ei, cursor, csr, E);

    // ---- layer 1 (H=8, C=16, concat) ----
    gemm_bf16<<<gemm_grid1, 256, 0, stream>>>(xb, N, Wt1, bias1, P, qWe);
    fused1_node<<<node_blocks, 256, 0, stream>>>(P, qWe, ea, We1, csr, rowptr, h1b, N);

    // ---- layer 2 (H=1, C=128, mean==identity) ----
    gemm_bf16<<<gemm_grid2, 256, 0, stream>>>(h1b, N, Wt2, bias2, P, qWe);
    fused2_node<<<node_blocks, 256, 0, stream>>>(P, qWe, ea, We2, csr, rowptr, (float*)d_out, N);
}

// Round 12
// 485.692 us; speedup vs baseline: 1.0195x; 1.0195x over previous
//
#include <hip/hip_runtime.h>
#include <math.h>

typedef __bf16 bf16x8 __attribute__((ext_vector_type(8)));
typedef float f32x4 __attribute__((ext_vector_type(4)));

// ---------------- bf16 helpers ----------------
__device__ __forceinline__ unsigned short f2bf(float f) {
    unsigned u = __float_as_uint(f);
    return (unsigned short)((u + 0x7fffu + ((u >> 16) & 1u)) >> 16);
}
__device__ __forceinline__ float2 bf2(unsigned u) {
    float2 r;
    r.x = __uint_as_float(u << 16);
    r.y = __uint_as_float(u & 0xffff0000u);
    return r;
}

// ---------------- prep: x -> bf16 ----------------
__global__ __launch_bounds__(256) void convert_x(
    const float* __restrict__ x, unsigned short* __restrict__ xb, int total)
{
    int g = blockIdx.x * blockDim.x + threadIdx.x;
    if (g < total) xb[g] = f2bf(x[g]);
}

// ---------------- prep: 640-col transposed bf16 weights + folded bias ----------------
// Output-column order == final P position (kv interleave baked in):
//   p in [0,256): cc = 2*(p>>2)+(p&1), W = (p&2)?Wv:Wk, +be folded.
//   [256,384)=q (Wq,bq); [384,512)=s (Ws,bs);
//   [512,640): qWe fused cols: Wt[c][d] = sum_i Wq[d,h*C+i]*We[kk*128+h*C+i].
__global__ __launch_bounds__(256) void prep_w(
    const float* __restrict__ Wq, const float* __restrict__ bq,
    const float* __restrict__ Wk, const float* __restrict__ bk,
    const float* __restrict__ Wv, const float* __restrict__ bv,
    const float* __restrict__ be,
    const float* __restrict__ Ws, const float* __restrict__ bs,
    const float* __restrict__ We, int H,
    unsigned short* __restrict__ Wt, float* __restrict__ bias)
{
    int g = blockIdx.x * blockDim.x + threadIdx.x;
    const int C = 128 / H;
    if (g < 640) {
        int p = g;
        float b;
        if (p < 256) {
            int cc = 2 * (p >> 2) + (p & 1);
            b = ((p & 2) ? bv[cc] : bk[cc]) + be[cc];
        }
        else if (p < 384) b = bq[p - 256];
        else if (p < 512) b = bs[p - 384];
        else {
            int c2 = p - 512, h = c2 >> 4, kk = c2 & 15;
            b = 0.f;
            if (h < H) for (int i = 0; i < C; ++i) b += bq[h * C + i] * We[kk * 128 + h * C + i];
        }
        bias[p] = b;
    }
    if (g >= 640 * 128) return;
    int p = g >> 7, d = g & 127;
    float w;
    if (p < 256) {
        int cc = 2 * (p >> 2) + (p & 1);
        w = (p & 2) ? Wv[d * 128 + cc] : Wk[d * 128 + cc];
    } else if (p < 384) {
        w = Wq[d * 128 + (p - 256)];
    } else if (p < 512) {
        w = Ws[d * 128 + (p - 384)];
    } else {
        int c2 = p - 512, h = c2 >> 4, kk = c2 & 15;
        w = 0.f;
        if (h < H) for (int i = 0; i < C; ++i) w += Wq[d * 128 + h * C + i] * We[kk * 128 + h * C + i];
    }
    Wt[(size_t)p * 128 + d] = f2bf(w);
}

// ---------------- MFMA bf16 GEMM: [P | qWe] = Xb[m,128] @ Wt + bias ----------------
// Round-0 structure (2D grid). B tile (64 cols x 128 k, 16 KB) staged in
// LDS. C-frag: col=lane&15, row=(lane>>4)*4+reg [m89/m91]. Epilogue via
// LDS for coalesced stores.
__global__ __launch_bounds__(256) void gemm_bf16(
    const unsigned short* __restrict__ Xb, int M,
    const unsigned short* __restrict__ Wt, const float* __restrict__ bias,
    unsigned short* __restrict__ P, float* __restrict__ qWe)
{
    __shared__ unsigned short Bs[64][136];
    __shared__ unsigned short tile[4][16][64];
    const int wv = threadIdx.x >> 6, lane = threadIdx.x & 63;
    const int row0 = blockIdx.x * 64 + wv * 16;
    const int n0 = blockIdx.y * 64;                 // [0,640)
    const int quad = lane >> 4, l16 = lane & 15;

    {   // stage Wt column-tile into LDS: 1024 x uint4, coalesced
        const uint4* gsrc = (const uint4*)(Wt + (size_t)n0 * 128);
#pragma unroll
        for (int u = 0; u < 4; ++u) {
            int v = threadIdx.x + u * 256;
            int col = v >> 4, k8 = v & 15;
            *(uint4*)(&Bs[col][k8 * 8]) = gsrc[v];
        }
    }
    __syncthreads();

    f32x4 acc[4] = {};
    int mrow = row0 + l16; if (mrow >= M) mrow = M - 1;  // clamp loads; stores guarded
    const int kb = quad * 8;
#pragma unroll
    for (int kk = 0; kk < 4; ++kk) {
        bf16x8 a = *(const bf16x8*)(Xb + (size_t)mrow * 128 + kk * 32 + kb);
#pragma unroll
        for (int f = 0; f < 4; ++f) {
            bf16x8 b = *(const bf16x8*)(&Bs[f * 16 + l16][kk * 32 + kb]);
            acc[f] = __builtin_amdgcn_mfma_f32_16x16x32_bf16(a, b, acc[f], 0, 0, 0);
        }
    }
    if (n0 < 512) {
#pragma unroll
        for (int f = 0; f < 4; ++f) {
            float bs = bias[n0 + f * 16 + l16];
#pragma unroll
            for (int r = 0; r < 4; ++r) {
                int row = quad * 4 + r;
                int col = f * 16 + l16;
                tile[wv][row][col ^ ((row & 3) << 4)] = f2bf(acc[f][r] + bs);
            }
        }
        __syncthreads();
        int row = lane >> 2, seg = lane & 3;
        int m = row0 + row;
        if (m < M) {
            const uint4* src = (const uint4*)&tile[wv][row][(seg ^ (row & 3)) << 4];
            uint4* dst = (uint4*)(P + (size_t)m * 512 + n0 + seg * 16);
            dst[0] = src[0];
            dst[1] = src[1];
        }
    } else {
#pragma unroll
        for (int f = 0; f < 4; ++f) {
            int c = n0 + f * 16 + l16;
            float bs = bias[c];
#pragma unroll
            for (int r = 0; r < 4; ++r) {
                int m = row0 + quad * 4 + r;
                if (m < M) qWe[(size_t)m * 128 + (c - 512)] = acc[f][r] + bs;
            }
        }
    }
}

// ---------------- CSR build (int atomics only) ----------------
__global__ __launch_bounds__(256) void degree_kernel(
    const int* __restrict__ ei, int* __restrict__ deg, int E)
{
    int e = blockIdx.x * blockDim.x + threadIdx.x;
    if (e < E) atomicAdd(&deg[ei[E + e]], 1);
}

// Block-parallel 3-phase prefix sum (r9 win: replaced 122us single-block scan).
__global__ __launch_bounds__(256) void scan_part1(
    const int* __restrict__ deg, int* __restrict__ partial, int N)
{
    __shared__ int s[256];
    const int t = threadIdx.x;
    const int g = blockIdx.x * 256 + t;
    int v = (g < N) ? deg[g] : 0;
    s[t] = v;
    __syncthreads();
    for (int ofs = 128; ofs > 0; ofs >>= 1) {
        if (t < ofs) s[t] += s[t + ofs];
        __syncthreads();
    }
    if (t == 0) partial[blockIdx.x] = s[0];
}

__global__ __launch_bounds__(256) void scan_part2(
    int* __restrict__ partial)   // 256 entries -> exclusive offsets in-place
{
    __shared__ int s[256];
    const int t = threadIdx.x;
    int v = partial[t];
    s[t] = v;
    __syncthreads();
    for (int ofs = 1; ofs < 256; ofs <<= 1) {
        int u = (t >= ofs) ? s[t - ofs] : 0;
        __syncthreads();
        s[t] += u;
        __syncthreads();
    }
    partial[t] = s[t] - v;   // exclusive
}

__global__ __launch_bounds__(256) void scan_part3(
    const int* __restrict__ deg, const int* __restrict__ offs,
    int* __restrict__ rowptr, int* __restrict__ cursor, int N)
{
    __shared__ int s[256];
    const int t = threadIdx.x;
    const int g = blockIdx.x * 256 + t;
    int v = (g < N) ? deg[g] : 0;
    s[t] = v;
    __syncthreads();
    for (int ofs = 1; ofs < 256; ofs <<= 1) {
        int u = (t >= ofs) ? s[t - ofs] : 0;
        __syncthreads();
        s[t] += u;
        __syncthreads();
    }
    const int incl = s[t];
    const int base = offs[blockIdx.x];
    if (g < N) {
        cursor[g] = base + incl - v;      // exclusive prefix
        rowptr[g + 1] = base + incl;      // inclusive prefix
    }
    if (g == 0) rowptr[0] = 0;
}

__global__ __launch_bounds__(256) void scatter_kernel(
    const int* __restrict__ ei, int* __restrict__ cursor,
    int2* __restrict__ csr, int E)
{
    int e = blockIdx.x * blockDim.x + threadIdx.x;
    if (e < E) {
        int pos = atomicAdd(&cursor[ei[E + e]], 1);
        csr[pos] = make_int2(ei[e], e);   // (src, edge id)
    }
}

// ---------------- fused score + online-softmax + aggregation ----------------
// ROUND 12: r10 quarter-wave chunk=4 (the 90us winner; r11's chunk=8 lost
// to VGPR/occupancy) + BLOCK-COOPERATIVE CSR STAGING. A block's 16 nodes
// are consecutive -> their csr rows are one contiguous range. Stage 17
// rowptr entries + the whole slice (avg 192 int2) into LDS in one coalesced
// burst; quarters then read edges via broadcast LDS reads. Removes 2 global
// latency epochs (rowptr, csr) + the se register + 2 shfls per edge from
// every node's serial chain. Fallback to global reads if slice > 2048
// (block-uniform; ~never at avg deg 12). Early-returns only AFTER the two
// barriers (no divergent-barrier deadlock).
// SPILL CANARY: fused1 WRITE_SIZE must stay 12.5 MB.
__global__ __launch_bounds__(256) void fused1_node(
    const unsigned short* __restrict__ P, const float* __restrict__ qWe,
    const float* __restrict__ ea, const float* __restrict__ We1,
    const int2* __restrict__ csr, const int* __restrict__ rowptr,
    unsigned short* __restrict__ h1, int N)
{
    __shared__ int  srow[17];
    __shared__ int2 slds[2048];
    const int tid = threadIdx.x;
    const int nb = blockIdx.x * 16;
    if (tid <= 16) {
        int nn = nb + tid;
        srow[tid] = rowptr[nn > N ? N : nn];
    }
    __syncthreads();
    const int b0 = srow[0];
    const int total = srow[16] - b0;
    const bool useLds = (total <= 2048);
    if (useLds) {
        for (int i = tid; i < total; i += 256) slds[i] = csr[b0 + i];
    }
    __syncthreads();

    const int lane = tid & 63;
    const int q = tid >> 4;              // quarter index in block [0,16)
    const int node = nb + q;
    if (node >= N) return;               // safe: no barriers below
    const int l16 = lane & 15;
    const int pbit = lane & 62;          // head-pair base (2 lanes per head)
    const int odd  = lane & 1;           // which ea-feature half this lane owns
    const int c0 = l16 * 8;              // 8 channels per lane

    const int beg = srow[q];
    const int deg = srow[q + 1] - beg;
    const int begL = beg - b0;

    uint4 su = *(const uint4*)(P + (size_t)node * 512 + 384 + c0);
    float2 sk0 = bf2(su.x), sk1 = bf2(su.y), sk2 = bf2(su.z), sk3 = bf2(su.w);
    if (deg == 0) {
        float o0 = sk0.x > 0.f ? sk0.x : 0.01f * sk0.x;
        float o1 = sk0.y > 0.f ? sk0.y : 0.01f * sk0.y;
        float o2 = sk1.x > 0.f ? sk1.x : 0.01f * sk1.x;
        float o3 = sk1.y > 0.f ? sk1.y : 0.01f * sk1.y;
        float o4 = sk2.x > 0.f ? sk2.x : 0.01f * sk2.x;
        float o5 = sk2.y > 0.f ? sk2.y : 0.01f * sk2.y;
        float o6 = sk3.x > 0.f ? sk3.x : 0.01f * sk3.x;
        float o7 = sk3.y > 0.f ? sk3.y : 0.01f * sk3.y;
        uint4 pk;
        pk.x = (unsigned)f2bf(o0) | ((unsigned)f2bf(o1) << 16);
        pk.y = (unsigned)f2bf(o2) | ((unsigned)f2bf(o3) << 16);
        pk.z = (unsigned)f2bf(o4) | ((unsigned)f2bf(o5) << 16);
        pk.w = (unsigned)f2bf(o6) | ((unsigned)f2bf(o7) << 16);
        *(uint4*)(h1 + (size_t)node * 128 + c0) = pk;
        return;
    }

    uint4 qu = *(const uint4*)(P + (size_t)node * 512 + 256 + c0);
    float2 q0 = bf2(qu.x), q1 = bf2(qu.y), q2 = bf2(qu.z), q3 = bf2(qu.w);
    float4 qwA = *(const float4*)(qWe + (size_t)node * 128 + c0);
    float4 qwB = *(const float4*)(qWe + (size_t)node * 128 + c0 + 4);

    float4 acA = make_float4(0.f, 0.f, 0.f, 0.f);   // v accum ch c0..c0+3
    float4 acB = make_float4(0.f, 0.f, 0.f, 0.f);   // v accum ch c0+4..+7
    float4 A2a = make_float4(0.f, 0.f, 0.f, 0.f);   // ea accum kk odd*8..+3
    float4 A2b = make_float4(0.f, 0.f, 0.f, 0.f);   // ea accum kk odd*8+4..+7
    float m = -INFINITY, lden = 0.f;

    for (int cb = 0; cb < deg; cb += 4) {
        const int lim = min(4, deg - cb);
        uint4 kva[4], kvb[4]; float4 eaA[4], eaB[4];
        // ---- gather phase: loads only ----
#pragma unroll
        for (int i = 0; i < 4; ++i) {
            if (i < lim) {
                int2 e = useLds ? slds[begL + cb + i] : csr[beg + cb + i];
                const unsigned short* kp = P + (size_t)e.x * 512 + l16 * 16;
                kva[i] = *(const uint4*)(kp);
                kvb[i] = *(const uint4*)(kp + 8);
                const float* ep = ea + (size_t)e.y * 16 + odd * 8;
                eaA[i] = *(const float4*)(ep);
                eaB[i] = *(const float4*)(ep + 4);
            }
        }
        // ---- score phase: owner lane odd==(i&1), slot i>>1 ----
        float s0 = -INFINITY, s1 = -INFINITY;
#pragma unroll
        for (int i = 0; i < 4; ++i) {
            if (i < lim) {
                float2 ka = bf2(kva[i].x), kb = bf2(kva[i].z);
                float2 kc = bf2(kvb[i].x), kd = bf2(kvb[i].z);
                float p = q0.x * ka.x + q0.y * ka.y + q1.x * kb.x + q1.y * kb.y
                        + q2.x * kc.x + q2.y * kc.y + q3.x * kd.x + q3.y * kd.y
                        + qwA.x * eaA[i].x + qwA.y * eaA[i].y
                        + qwA.z * eaA[i].z + qwA.w * eaA[i].w
                        + qwB.x * eaB[i].x + qwB.y * eaB[i].y
                        + qwB.z * eaB[i].z + qwB.w * eaB[i].w;
                p += __shfl_xor(p, 1, 64);    // head-pair sum
                float pv = p * 0.25f;         // 1/sqrt(16)
                if (odd == (i & 1)) { if (i < 2) s0 = pv; else s1 = pv; }
            }
        }
        // ---- online softmax update (per head; pair-local) ----
        float cm = fmaxf(s0, s1);
        cm = fmaxf(cm, __shfl_xor(cm, 1, 64));
        float m_new = fmaxf(m, cm);
        float scale = __expf(m - m_new);      // first chunk: exp(-inf)=0
        float e0 = __expf(s0 - m_new);        // unassigned slots: 0
        float e1 = __expf(s1 - m_new);
        float ds = e0 + e1;
        ds += __shfl_xor(ds, 1, 64);
        lden = lden * scale + ds;
        acA.x *= scale; acA.y *= scale; acA.z *= scale; acA.w *= scale;
        acB.x *= scale; acB.y *= scale; acB.z *= scale; acB.w *= scale;
        A2a.x *= scale; A2a.y *= scale; A2a.z *= scale; A2a.w *= scale;
        A2b.x *= scale; A2b.y *= scale; A2b.z *= scale; A2b.w *= scale;
        m = m_new;
        // ---- accumulate phase ----
#pragma unroll
        for (int i = 0; i < 4; ++i) {
            if (i < lim) {
                float w = __shfl((i < 2) ? e0 : e1, pbit | (i & 1), 64);
                float2 va = bf2(kva[i].y), vb = bf2(kva[i].w);
                float2 vc = bf2(kvb[i].y), vd = bf2(kvb[i].w);
                acA.x += w * va.x; acA.y += w * va.y;
                acA.z += w * vb.x; acA.w += w * vb.y;
                acB.x += w * vc.x; acB.y += w * vc.y;
                acB.z += w * vd.x; acB.w += w * vd.y;
                A2a.x += w * eaA[i].x; A2a.y += w * eaA[i].y;
                A2a.z += w * eaA[i].z; A2a.w += w * eaA[i].w;
                A2b.x += w * eaB[i].x; A2b.y += w * eaB[i].y;
                A2b.z += w * eaB[i].z; A2b.w += w * eaB[i].w;
            }
        }
    }

    // expand A_h through We1 (pair-local). Lane pbit|(k>>3) holds feature k
    // (component k&7 of its A2a/A2b).
    float ex0 = 0.f, ex1 = 0.f, ex2 = 0.f, ex3 = 0.f;
    float ex4 = 0.f, ex5 = 0.f, ex6 = 0.f, ex7 = 0.f;
#pragma unroll
    for (int k = 0; k < 16; ++k) {
        float comp = (k & 7) == 0 ? A2a.x : (k & 7) == 1 ? A2a.y :
                     (k & 7) == 2 ? A2a.z : (k & 7) == 3 ? A2a.w :
                     (k & 7) == 4 ? A2b.x : (k & 7) == 5 ? A2b.y :
                     (k & 7) == 6 ? A2b.z : A2b.w;
        float ak = __shfl(comp, pbit | (k >> 3), 64);
        const float* wp = We1 + k * 128 + c0;
        float4 w4a = *(const float4*)(wp);
        float4 w4b = *(const float4*)(wp + 4);
        ex0 += ak * w4a.x; ex1 += ak * w4a.y; ex2 += ak * w4a.z; ex3 += ak * w4a.w;
        ex4 += ak * w4b.x; ex5 += ak * w4b.y; ex6 += ak * w4b.z; ex7 += ak * w4b.w;
    }
    float inv = 1.f / (lden + 1e-16f);
    float o0 = (acA.x + ex0) * inv + sk0.x;
    float o1 = (acA.y + ex1) * inv + sk0.y;
    float o2 = (acA.z + ex2) * inv + sk1.x;
    float o3 = (acA.w + ex3) * inv + sk1.y;
    float o4 = (acB.x + ex4) * inv + sk2.x;
    float o5 = (acB.y + ex5) * inv + sk2.y;
    float o6 = (acB.z + ex6) * inv + sk3.x;
    float o7 = (acB.w + ex7) * inv + sk3.y;
    o0 = o0 > 0.f ? o0 : 0.01f * o0;
    o1 = o1 > 0.f ? o1 : 0.01f * o1;
    o2 = o2 > 0.f ? o2 : 0.01f * o2;
    o3 = o3 > 0.f ? o3 : 0.01f * o3;
    o4 = o4 > 0.f ? o4 : 0.01f * o4;
    o5 = o5 > 0.f ? o5 : 0.01f * o5;
    o6 = o6 > 0.f ? o6 : 0.01f * o6;
    o7 = o7 > 0.f ? o7 : 0.01f * o7;
    uint4 pk;
    pk.x = (unsigned)f2bf(o0) | ((unsigned)f2bf(o1) << 16);
    pk.y = (unsigned)f2bf(o2) | ((unsigned)f2bf(o3) << 16);
    pk.z = (unsigned)f2bf(o4) | ((unsigned)f2bf(o5) << 16);
    pk.w = (unsigned)f2bf(o6) | ((unsigned)f2bf(o7) << 16);
    *(uint4*)(h1 + (size_t)node * 128 + c0) = pk;
}

// Layer 2: H=1, C=128. One node per 16-lane quarter; 16-lane dot per edge;
// lanes 0..3 of the quarter hold the chunk's scores. Same block-cooperative
// CSR staging as fused1_node.
__global__ __launch_bounds__(256) void fused2_node(
    const unsigned short* __restrict__ P, const float* __restrict__ qWe,
    const float* __restrict__ ea, const float* __restrict__ We2,
    const int2* __restrict__ csr, const int* __restrict__ rowptr,
    float* __restrict__ out, int N)
{
    __shared__ int  srow[17];
    __shared__ int2 slds[2048];
    const int tid = threadIdx.x;
    const int nb = blockIdx.x * 16;
    if (tid <= 16) {
        int nn = nb + tid;
        srow[tid] = rowptr[nn > N ? N : nn];
    }
    __syncthreads();
    const int b0 = srow[0];
    const int total = srow[16] - b0;
    const bool useLds = (total <= 2048);
    if (useLds) {
        for (int i = tid; i < total; i += 256) slds[i] = csr[b0 + i];
    }
    __syncthreads();

    const int lane = tid & 63;
    const int q = tid >> 4;
    const int node = nb + q;
    if (node >= N) return;               // safe: no barriers below
    const int l16 = lane & 15;
    const int qbit = lane & 48;
    const int c0 = l16 * 8;

    const int beg = srow[q];
    const int deg = srow[q + 1] - beg;
    const int begL = beg - b0;

    uint4 su = *(const uint4*)(P + (size_t)node * 512 + 384 + c0);
    float2 sk0 = bf2(su.x), sk1 = bf2(su.y), sk2 = bf2(su.z), sk3 = bf2(su.w);
    float* outp = out + (size_t)node * 128 + c0;
    if (deg == 0) {
        *(float4*)outp = make_float4(sk0.x, sk0.y, sk1.x, sk1.y);
        *(float4*)(outp + 4) = make_float4(sk2.x, sk2.y, sk3.x, sk3.y);
        return;
    }

    uint4 qu = *(const uint4*)(P + (size_t)node * 512 + 256 + c0);
    float2 q0 = bf2(qu.x), q1 = bf2(qu.y), q2 = bf2(qu.z), q3 = bf2(qu.w);
    float qw = qWe[(size_t)node * 128 + l16];

    float4 acA = make_float4(0.f, 0.f, 0.f, 0.f);
    float4 acB = make_float4(0.f, 0.f, 0.f, 0.f);
    float accA = 0.f;
    float m = -INFINITY, lden = 0.f;

    for (int cb = 0; cb < deg; cb += 4) {
        const int lim = min(4, deg - cb);
        uint4 kva[4], kvb[4]; float eav[4];
        // ---- gather phase ----
#pragma unroll
        for (int i = 0; i < 4; ++i) {
            if (i < lim) {
                int2 e = useLds ? slds[begL + cb + i] : csr[beg + cb + i];
                const unsigned short* kp = P + (size_t)e.x * 512 + l16 * 16;
                kva[i] = *(const uint4*)(kp);
                kvb[i] = *(const uint4*)(kp + 8);
                eav[i] = ea[(size_t)e.y * 16 + l16];
            }
        }
        // ---- score phase (16-lane dot within quarter) ----
        float my_s = -INFINITY;
#pragma unroll
        for (int i = 0; i < 4; ++i) {
            if (i < lim) {
                float2 ka = bf2(kva[i].x), kb = bf2(kva[i].z);
                float2 kc = bf2(kvb[i].x), kd = bf2(kvb[i].z);
                float p = q0.x * ka.x + q0.y * ka.y + q1.x * kb.x + q1.y * kb.y
                        + q2.x * kc.x + q2.y * kc.y + q3.x * kd.x + q3.y * kd.y
                        + qw * eav[i];
                p += __shfl_xor(p, 1, 64);
                p += __shfl_xor(p, 2, 64);
                p += __shfl_xor(p, 4, 64);
                p += __shfl_xor(p, 8, 64);     // quarter-wide reduction
                if (l16 == i) my_s = p * 0.08838834764831845f;  // 1/sqrt(128)
            }
        }
        // ---- online softmax (quarter-local) ----
        float cm = my_s;
#pragma unroll
        for (int mk = 1; mk < 16; mk <<= 1) cm = fmaxf(cm, __shfl_xor(cm, mk, 64));
        float m_new = fmaxf(m, cm);
        float scale = __expf(m - m_new);
        float ew = __expf(my_s - m_new);   // non-slot: 0
        float ds = ew;
#pragma unroll
        for (int mk = 1; mk < 16; mk <<= 1) ds += __shfl_xor(ds, mk, 64);
        lden = lden * scale + ds;
        acA.x *= scale; acA.y *= scale; acA.z *= scale; acA.w *= scale;
        acB.x *= scale; acB.y *= scale; acB.z *= scale; acB.w *= scale;
        accA *= scale;
        m = m_new;
        // ---- accumulate ----
#pragma unroll
        for (int i = 0; i < 4; ++i) {
            if (i < lim) {
                float w = __shfl(ew, qbit | i, 64);
                float2 va = bf2(kva[i].y), vb = bf2(kva[i].w);
                float2 vc = bf2(kvb[i].y), vd = bf2(kvb[i].w);
                acA.x += w * va.x; acA.y += w * va.y;
                acA.z += w * vb.x; acA.w += w * vb.y;
                acB.x += w * vc.x; acB.y += w * vc.y;
                acB.z += w * vd.x; acB.w += w * vd.y;
                accA += w * eav[i];
            }
        }
    }

    float ex0 = 0.f, ex1 = 0.f, ex2 = 0.f, ex3 = 0.f;
    float ex4 = 0.f, ex5 = 0.f, ex6 = 0.f, ex7 = 0.f;
#pragma unroll
    for (int k = 0; k < 16; ++k) {
        float ak = __shfl(accA, qbit | k, 64);   // lane qbit+k holds feature k
        const float* wp = We2 + k * 128 + c0;
        float4 w4a = *(const float4*)(wp);
        float4 w4b = *(const float4*)(wp + 4);
        ex0 += ak * w4a.x; ex1 += ak * w4a.y; ex2 += ak * w4a.z; ex3 += ak * w4a.w;
        ex4 += ak * w4b.x; ex5 += ak * w4b.y; ex6 += ak * w4b.z; ex7 += ak * w4b.w;
    }
    float inv = 1.f / (lden + 1e-16f);
    float4 oA, oB;
    oA.x = (acA.x + ex0) * inv + sk0.x;
    oA.y = (acA.y + ex1) * inv + sk0.y;
    oA.z = (acA.z + ex2) * inv + sk1.x;
    oA.w = (acA.w + ex3) * inv + sk1.y;
    oB.x = (acB.x + ex4) * inv + sk2.x;
    oB.y = (acB.y + ex5) * inv + sk2.y;
    oB.z = (acB.z + ex6) * inv + sk3.x;
    oB.w = (acB.w + ex7) * inv + sk3.y;
    *(float4*)outp = oA;
    *(float4*)(outp + 4) = oB;
}

// ---------------- launch ----------------
extern "C" void kernel_launch(void* const* d_in, const int* in_sizes, int n_in,
                              void* d_out, int out_size, void* d_ws, size_t ws_size,
                              hipStream_t stream)
{
    const float* x  = (const float*)d_in[0];
    const int*   ei = (const int*)d_in[1];
    const float* ea = (const float*)d_in[2];
    const float *Wq1 = (const float*)d_in[3],  *bq1 = (const float*)d_in[4];
    const float *Wk1 = (const float*)d_in[5],  *bk1 = (const float*)d_in[6];
    const float *Wv1 = (const float*)d_in[7],  *bv1 = (const float*)d_in[8];
    const float *We1 = (const float*)d_in[9],  *be1 = (const float*)d_in[10];
    const float *Ws1 = (const float*)d_in[11], *bs1 = (const float*)d_in[12];
    const float *Wq2 = (const float*)d_in[13], *bq2 = (const float*)d_in[14];
    const float *Wk2 = (const float*)d_in[15], *bk2 = (const float*)d_in[16];
    const float *Wv2 = (const float*)d_in[17], *bv2 = (const float*)d_in[18];
    const float *We2 = (const float*)d_in[19], *be2 = (const float*)d_in[20];
    const float *Ws2 = (const float*)d_in[21], *bs2 = (const float*)d_in[22];

    const int N = in_sizes[0] / 128;
    const int E = in_sizes[1] / 2;

    char* ws = (char*)d_ws;
    size_t off = 0;
    auto alloc = [&](size_t bytes) -> void* {
        void* p = ws + off;
        off = (off + bytes + 255) & ~(size_t)255;
        return p;
    };
    unsigned short* xb  = (unsigned short*)alloc((size_t)N * 128 * 2);
    unsigned short* P   = (unsigned short*)alloc((size_t)N * 512 * 2);  // bf16 [kv-interleave | q | s]
    unsigned short* h1b = (unsigned short*)alloc((size_t)N * 128 * 2);
    unsigned short* Wt1 = (unsigned short*)alloc((size_t)640 * 128 * 2);
    unsigned short* Wt2 = (unsigned short*)alloc((size_t)640 * 128 * 2);
    float* bias1 = (float*)alloc(640 * 4);
    float* bias2 = (float*)alloc(640 * 4);
    float* qWe   = (float*)alloc((size_t)N * 128 * 4);
    int*  deg    = (int*)alloc((size_t)N * 4);
    int*  rowptr = (int*)alloc((size_t)(N + 1) * 4);
    int*  cursor = (int*)alloc((size_t)N * 4);
    int*  partial= (int*)alloc(256 * 4);
    int2* csr    = (int2*)alloc((size_t)E * 8);

    dim3 gemm_grid1((N + 63) / 64, 10);
    dim3 gemm_grid2((N + 63) / 64, 9);   // layer-2 qWe needs only cols [512,528)
    const int tn = N * 128;
    const int node_blocks = (N + 15) / 16;   // 16 nodes (16 quarter-waves) per 256-thread block
    const int prep_blocks = (640 * 128 + 255) / 256;
    const int scan_blocks = (N + 255) / 256; // <=256 required (N<=65536)

    // ---- prep (independent of everything else) ----
    convert_x<<<(tn + 255) / 256, 256, 0, stream>>>(x, xb, tn);
    prep_w<<<prep_blocks, 256, 0, stream>>>(Wq1, bq1, Wk1, bk1, Wv1, bv1, be1, Ws1, bs1, We1, 8, Wt1, bias1);
    prep_w<<<prep_blocks, 256, 0, stream>>>(Wq2, bq2, Wk2, bk2, Wv2, bv2, be2, Ws2, bs2, We2, 1, Wt2, bias2);

    // ---- CSR build (shared by both layers) ----
    hipMemsetAsync(deg, 0, (size_t)N * 4, stream);
    hipMemsetAsync(partial, 0, 256 * 4, stream);
    degree_kernel<<<(E + 255) / 256, 256, 0, stream>>>(ei, deg, E);
    scan_part1<<<scan_blocks, 256, 0, stream>>>(deg, partial, N);
    scan_part2<<<1, 256, 0, stream>>>(partial);
    scan_part3<<<scan_blocks, 256, 0, stream>>>(deg, partial, rowptr, cursor, N);
    scatter_kernel<<<(E + 255) / 256, 256, 0, stream>>>(ei, cursor, csr, E);

    // ---- layer 1 (H=8, C=16, concat) ----
    gemm_bf16<<<gemm_grid1, 256, 0, stream>>>(xb, N, Wt1, bias1, P, qWe);
    fused1_node<<<node_blocks, 256, 0, stream>>>(P, qWe, ea, We1, csr, rowptr, h1b, N);

    // ---- layer 2 (H=1, C=128, mean==identity) ----
    gemm_bf16<<<gemm_grid2, 256, 0, stream>>>(h1b, N, Wt2, bias2, P, qWe);
    fused2_node<<<node_blocks, 256, 0, stream>>>(P, qWe, ea, We2, csr, rowptr, (float*)d_out, N);
}

// Round 13
// 474.776 us; speedup vs baseline: 1.0430x; 1.0230x over previous
//
#include <hip/hip_runtime.h>
#include <math.h>

typedef __bf16 bf16x8 __attribute__((ext_vector_type(8)));
typedef float f32x4 __attribute__((ext_vector_type(4)));

// ---------------- bf16 helpers ----------------
__device__ __forceinline__ unsigned short f2bf(float f) {
    unsigned u = __float_as_uint(f);
    return (unsigned short)((u + 0x7fffu + ((u >> 16) & 1u)) >> 16);
}
__device__ __forceinline__ float2 bf2(unsigned u) {
    float2 r;
    r.x = __uint_as_float(u << 16);
    r.y = __uint_as_float(u & 0xffff0000u);
    return r;
}

// ---------------- prep: x -> bf16 ----------------
__global__ __launch_bounds__(256) void convert_x(
    const float* __restrict__ x, unsigned short* __restrict__ xb, int total)
{
    int g = blockIdx.x * blockDim.x + threadIdx.x;
    if (g < total) xb[g] = f2bf(x[g]);
}

// ---------------- prep: 640-col transposed bf16 weights + folded bias ----------------
// Output-column order == final P position (kv interleave baked in):
//   p in [0,256): cc = 2*(p>>2)+(p&1), W = (p&2)?Wv:Wk, +be folded.
//   [256,384)=q (Wq,bq); [384,512)=s (Ws,bs);
//   [512,640): qWe fused cols: Wt[c][d] = sum_i Wq[d,h*C+i]*We[kk*128+h*C+i].
__global__ __launch_bounds__(256) void prep_w(
    const float* __restrict__ Wq, const float* __restrict__ bq,
    const float* __restrict__ Wk, const float* __restrict__ bk,
    const float* __restrict__ Wv, const float* __restrict__ bv,
    const float* __restrict__ be,
    const float* __restrict__ Ws, const float* __restrict__ bs,
    const float* __restrict__ We, int H,
    unsigned short* __restrict__ Wt, float* __restrict__ bias)
{
    int g = blockIdx.x * blockDim.x + threadIdx.x;
    const int C = 128 / H;
    if (g < 640) {
        int p = g;
        float b;
        if (p < 256) {
            int cc = 2 * (p >> 2) + (p & 1);
            b = ((p & 2) ? bv[cc] : bk[cc]) + be[cc];
        }
        else if (p < 384) b = bq[p - 256];
        else if (p < 512) b = bs[p - 384];
        else {
            int c2 = p - 512, h = c2 >> 4, kk = c2 & 15;
            b = 0.f;
            if (h < H) for (int i = 0; i < C; ++i) b += bq[h * C + i] * We[kk * 128 + h * C + i];
        }
        bias[p] = b;
    }
    if (g >= 640 * 128) return;
    int p = g >> 7, d = g & 127;
    float w;
    if (p < 256) {
        int cc = 2 * (p >> 2) + (p & 1);
        w = (p & 2) ? Wv[d * 128 + cc] : Wk[d * 128 + cc];
    } else if (p < 384) {
        w = Wq[d * 128 + (p - 256)];
    } else if (p < 512) {
        w = Ws[d * 128 + (p - 384)];
    } else {
        int c2 = p - 512, h = c2 >> 4, kk = c2 & 15;
        w = 0.f;
        if (h < H) for (int i = 0; i < C; ++i) w += Wq[d * 128 + h * C + i] * We[kk * 128 + h * C + i];
    }
    Wt[(size_t)p * 128 + d] = f2bf(w);
}

// ---------------- MFMA bf16 GEMM: [P | qWe] = Xb[m,128] @ Wt + bias ----------------
// ROUND 13: 2 row-tiles (32 rows) per wave. Wave-supply model (validated on
// fused kernels r6/r7/r8) applied to gemm: old grid 782x10x4 = 31280 waves
// of only 16 MFMA each ~ 89 us at the ~350 waves/us launch ceiling. Halving
// wave count (each wave reuses the LDS B-tile for 2 row-tiles; ds_reads
// reused 2x) should halve gemm time. B tile (64 cols x 128 k, 16 KB) in
// LDS; C-frag: col=lane&15, row=(lane>>4)*4+reg [m89/m91].
__global__ __launch_bounds__(256) void gemm_bf16(
    const unsigned short* __restrict__ Xb, int M,
    const unsigned short* __restrict__ Wt, const float* __restrict__ bias,
    unsigned short* __restrict__ P, float* __restrict__ qWe)
{
    __shared__ unsigned short Bs[64][136];
    __shared__ unsigned short tile[4][32][64];
    const int wv = threadIdx.x >> 6, lane = threadIdx.x & 63;
    const int row0 = blockIdx.x * 128 + wv * 32;    // 32 rows per wave
    const int n0 = blockIdx.y * 64;                 // [0,640)
    const int quad = lane >> 4, l16 = lane & 15;

    {   // stage Wt column-tile into LDS: 1024 x uint4, coalesced
        const uint4* gsrc = (const uint4*)(Wt + (size_t)n0 * 128);
#pragma unroll
        for (int u = 0; u < 4; ++u) {
            int v = threadIdx.x + u * 256;
            int col = v >> 4, k8 = v & 15;
            *(uint4*)(&Bs[col][k8 * 8]) = gsrc[v];
        }
    }
    __syncthreads();

    f32x4 acc[2][4] = {};
    const int kb = quad * 8;
    bf16x8 a[2][4];
#pragma unroll
    for (int r2 = 0; r2 < 2; ++r2) {
        int mrow = row0 + r2 * 16 + l16; if (mrow >= M) mrow = M - 1;  // clamp; stores guarded
#pragma unroll
        for (int kk = 0; kk < 4; ++kk)
            a[r2][kk] = *(const bf16x8*)(Xb + (size_t)mrow * 128 + kk * 32 + kb);
    }
#pragma unroll
    for (int kk = 0; kk < 4; ++kk) {
#pragma unroll
        for (int f = 0; f < 4; ++f) {
            bf16x8 b = *(const bf16x8*)(&Bs[f * 16 + l16][kk * 32 + kb]);
            acc[0][f] = __builtin_amdgcn_mfma_f32_16x16x32_bf16(a[0][kk], b, acc[0][f], 0, 0, 0);
            acc[1][f] = __builtin_amdgcn_mfma_f32_16x16x32_bf16(a[1][kk], b, acc[1][f], 0, 0, 0);
        }
    }
    if (n0 < 512) {
#pragma unroll
        for (int r2 = 0; r2 < 2; ++r2) {
#pragma unroll
            for (int f = 0; f < 4; ++f) {
                float bs = bias[n0 + f * 16 + l16];
#pragma unroll
                for (int r = 0; r < 4; ++r) {
                    int row = quad * 4 + r;
                    int col = f * 16 + l16;
                    tile[wv][r2 * 16 + row][col ^ ((row & 3) << 4)] = f2bf(acc[r2][f][r] + bs);
                }
            }
        }
        __syncthreads();
        int row = lane >> 2, seg = lane & 3;
#pragma unroll
        for (int rr = 0; rr < 2; ++rr) {
            int m = row0 + rr * 16 + row;
            if (m < M) {
                const uint4* src = (const uint4*)&tile[wv][rr * 16 + row][(seg ^ (row & 3)) << 4];
                uint4* dst = (uint4*)(P + (size_t)m * 512 + n0 + seg * 16);
                dst[0] = src[0];
                dst[1] = src[1];
            }
        }
    } else {
#pragma unroll
        for (int r2 = 0; r2 < 2; ++r2) {
#pragma unroll
            for (int f = 0; f < 4; ++f) {
                int c = n0 + f * 16 + l16;
                float bs = bias[c];
#pragma unroll
                for (int r = 0; r < 4; ++r) {
                    int m = row0 + r2 * 16 + quad * 4 + r;
                    if (m < M) qWe[(size_t)m * 128 + (c - 512)] = acc[r2][f][r] + bs;
                }
            }
        }
    }
}

// ---------------- CSR build (int atomics only) ----------------
__global__ __launch_bounds__(256) void degree_kernel(
    const int* __restrict__ ei, int* __restrict__ deg, int E)
{
    int e = blockIdx.x * blockDim.x + threadIdx.x;
    if (e < E) atomicAdd(&deg[ei[E + e]], 1);
}

// Block-parallel 3-phase prefix sum (r9 win: replaced 122us single-block scan).
__global__ __launch_bounds__(256) void scan_part1(
    const int* __restrict__ deg, int* __restrict__ partial, int N)
{
    __shared__ int s[256];
    const int t = threadIdx.x;
    const int g = blockIdx.x * 256 + t;
    int v = (g < N) ? deg[g] : 0;
    s[t] = v;
    __syncthreads();
    for (int ofs = 128; ofs > 0; ofs >>= 1) {
        if (t < ofs) s[t] += s[t + ofs];
        __syncthreads();
    }
    if (t == 0) partial[blockIdx.x] = s[0];
}

__global__ __launch_bounds__(256) void scan_part2(
    int* __restrict__ partial)   // 256 entries -> exclusive offsets in-place
{
    __shared__ int s[256];
    const int t = threadIdx.x;
    int v = partial[t];
    s[t] = v;
    __syncthreads();
    for (int ofs = 1; ofs < 256; ofs <<= 1) {
        int u = (t >= ofs) ? s[t - ofs] : 0;
        __syncthreads();
        s[t] += u;
        __syncthreads();
    }
    partial[t] = s[t] - v;   // exclusive
}

__global__ __launch_bounds__(256) void scan_part3(
    const int* __restrict__ deg, const int* __restrict__ offs,
    int* __restrict__ rowptr, int* __restrict__ cursor, int N)
{
    __shared__ int s[256];
    const int t = threadIdx.x;
    const int g = blockIdx.x * 256 + t;
    int v = (g < N) ? deg[g] : 0;
    s[t] = v;
    __syncthreads();
    for (int ofs = 1; ofs < 256; ofs <<= 1) {
        int u = (t >= ofs) ? s[t - ofs] : 0;
        __syncthreads();
        s[t] += u;
        __syncthreads();
    }
    const int incl = s[t];
    const int base = offs[blockIdx.x];
    if (g < N) {
        cursor[g] = base + incl - v;      // exclusive prefix
        rowptr[g + 1] = base + incl;      // inclusive prefix
    }
    if (g == 0) rowptr[0] = 0;
}

__global__ __launch_bounds__(256) void scatter_kernel(
    const int* __restrict__ ei, int* __restrict__ cursor,
    int2* __restrict__ csr, int E)
{
    int e = blockIdx.x * blockDim.x + threadIdx.x;
    if (e < E) {
        int pos = atomicAdd(&cursor[ei[E + e]], 1);
        csr[pos] = make_int2(ei[e], e);   // (src, edge id)
    }
}

// ---------------- fused score + online-softmax + aggregation ----------------
// r10 WINNER (byte-identical): one node per 16-lane quarter-wave, chunk=4.
// r11 (chunk=8, VGPR 108) and r12 (LDS CSR staging) both regressed — this
// is the measured optimum of the geometry/chunk/staging space at 90 us.
__global__ __launch_bounds__(256) void fused1_node(
    const unsigned short* __restrict__ P, const float* __restrict__ qWe,
    const float* __restrict__ ea, const float* __restrict__ We1,
    const int2* __restrict__ csr, const int* __restrict__ rowptr,
    unsigned short* __restrict__ h1, int N)
{
    const int lane = threadIdx.x & 63;
    const int node = blockIdx.x * 16 + (threadIdx.x >> 4);   // one node per quarter
    if (node >= N) return;
    const int l16 = lane & 15;
    const int qbit = lane & 48;       // quarter base (shfl indices)
    const int pbit = lane & 62;       // head-pair base (2 lanes per head)
    const int odd  = lane & 1;        // which ea-feature half this lane owns
    const int c0 = l16 * 8;           // 8 channels per lane

    const int beg = rowptr[node];
    const int deg = rowptr[node + 1] - beg;

    uint4 su = *(const uint4*)(P + (size_t)node * 512 + 384 + c0);
    float2 sk0 = bf2(su.x), sk1 = bf2(su.y), sk2 = bf2(su.z), sk3 = bf2(su.w);
    if (deg == 0) {
        float o0 = sk0.x > 0.f ? sk0.x : 0.01f * sk0.x;
        float o1 = sk0.y > 0.f ? sk0.y : 0.01f * sk0.y;
        float o2 = sk1.x > 0.f ? sk1.x : 0.01f * sk1.x;
        float o3 = sk1.y > 0.f ? sk1.y : 0.01f * sk1.y;
        float o4 = sk2.x > 0.f ? sk2.x : 0.01f * sk2.x;
        float o5 = sk2.y > 0.f ? sk2.y : 0.01f * sk2.y;
        float o6 = sk3.x > 0.f ? sk3.x : 0.01f * sk3.x;
        float o7 = sk3.y > 0.f ? sk3.y : 0.01f * sk3.y;
        uint4 pk;
        pk.x = (unsigned)f2bf(o0) | ((unsigned)f2bf(o1) << 16);
        pk.y = (unsigned)f2bf(o2) | ((unsigned)f2bf(o3) << 16);
        pk.z = (unsigned)f2bf(o4) | ((unsigned)f2bf(o5) << 16);
        pk.w = (unsigned)f2bf(o6) | ((unsigned)f2bf(o7) << 16);
        *(uint4*)(h1 + (size_t)node * 128 + c0) = pk;
        return;
    }

    uint4 qu = *(const uint4*)(P + (size_t)node * 512 + 256 + c0);
    float2 q0 = bf2(qu.x), q1 = bf2(qu.y), q2 = bf2(qu.z), q3 = bf2(qu.w);
    float4 qwA = *(const float4*)(qWe + (size_t)node * 128 + c0);
    float4 qwB = *(const float4*)(qWe + (size_t)node * 128 + c0 + 4);

    float4 acA = make_float4(0.f, 0.f, 0.f, 0.f);   // v accum ch c0..c0+3
    float4 acB = make_float4(0.f, 0.f, 0.f, 0.f);   // v accum ch c0+4..+7
    float4 A2a = make_float4(0.f, 0.f, 0.f, 0.f);   // ea accum kk odd*8..+3
    float4 A2b = make_float4(0.f, 0.f, 0.f, 0.f);   // ea accum kk odd*8+4..+7
    float m = -INFINITY, lden = 0.f;

    int2 se = make_int2(0, 0);
    if (l16 < deg) se = csr[beg + l16];

    for (int blk = 0; blk < deg; blk += 16) {
        if (blk) se = (blk + l16 < deg) ? csr[beg + blk + l16] : make_int2(0, 0);
        const int bcnt = min(16, deg - blk);
        for (int cb = 0; cb < bcnt; cb += 4) {
            const int lim = min(4, bcnt - cb);
            uint4 kva[4], kvb[4]; float4 eaA[4], eaB[4];
            // ---- gather phase: loads only ----
#pragma unroll
            for (int i = 0; i < 4; ++i) {
                if (i < lim) {   // quarter-uniform
                    int jc = min(cb + i, bcnt - 1);
                    int sb = __shfl(se.x, qbit | jc, 64);
                    int eb = __shfl(se.y, qbit | jc, 64);
                    const unsigned short* kp = P + (size_t)sb * 512 + l16 * 16;
                    kva[i] = *(const uint4*)(kp);
                    kvb[i] = *(const uint4*)(kp + 8);
                    const float* ep = ea + (size_t)eb * 16 + odd * 8;
                    eaA[i] = *(const float4*)(ep);
                    eaB[i] = *(const float4*)(ep + 4);
                }
            }
            // ---- score phase: owner lane odd==(i&1), slot i>>1 ----
            float s0 = -INFINITY, s1 = -INFINITY;
#pragma unroll
            for (int i = 0; i < 4; ++i) {
                if (i < lim) {
                    float2 ka = bf2(kva[i].x), kb = bf2(kva[i].z);
                    float2 kc = bf2(kvb[i].x), kd = bf2(kvb[i].z);
                    float p = q0.x * ka.x + q0.y * ka.y + q1.x * kb.x + q1.y * kb.y
                            + q2.x * kc.x + q2.y * kc.y + q3.x * kd.x + q3.y * kd.y
                            + qwA.x * eaA[i].x + qwA.y * eaA[i].y
                            + qwA.z * eaA[i].z + qwA.w * eaA[i].w
                            + qwB.x * eaB[i].x + qwB.y * eaB[i].y
                            + qwB.z * eaB[i].z + qwB.w * eaB[i].w;
                    p += __shfl_xor(p, 1, 64);    // head-pair sum
                    float pv = p * 0.25f;         // 1/sqrt(16)
                    if (odd == (i & 1)) { if (i < 2) s0 = pv; else s1 = pv; }
                }
            }
            // ---- online softmax update (per head; pair-local) ----
            float cm = fmaxf(s0, s1);
            cm = fmaxf(cm, __shfl_xor(cm, 1, 64));
            float m_new = fmaxf(m, cm);
            float scale = __expf(m - m_new);      // first chunk: exp(-inf)=0
            float e0 = __expf(s0 - m_new);        // unassigned slots: 0
            float e1 = __expf(s1 - m_new);
            float ds = e0 + e1;
            ds += __shfl_xor(ds, 1, 64);
            lden = lden * scale + ds;
            acA.x *= scale; acA.y *= scale; acA.z *= scale; acA.w *= scale;
            acB.x *= scale; acB.y *= scale; acB.z *= scale; acB.w *= scale;
            A2a.x *= scale; A2a.y *= scale; A2a.z *= scale; A2a.w *= scale;
            A2b.x *= scale; A2b.y *= scale; A2b.z *= scale; A2b.w *= scale;
            m = m_new;
            // ---- accumulate phase ----
#pragma unroll
            for (int i = 0; i < 4; ++i) {
                if (i < lim) {
                    float w = __shfl((i < 2) ? e0 : e1, pbit | (i & 1), 64);
                    float2 va = bf2(kva[i].y), vb = bf2(kva[i].w);
                    float2 vc = bf2(kvb[i].y), vd = bf2(kvb[i].w);
                    acA.x += w * va.x; acA.y += w * va.y;
                    acA.z += w * vb.x; acA.w += w * vb.y;
                    acB.x += w * vc.x; acB.y += w * vc.y;
                    acB.z += w * vd.x; acB.w += w * vd.y;
                    A2a.x += w * eaA[i].x; A2a.y += w * eaA[i].y;
                    A2a.z += w * eaA[i].z; A2a.w += w * eaA[i].w;
                    A2b.x += w * eaB[i].x; A2b.y += w * eaB[i].y;
                    A2b.z += w * eaB[i].z; A2b.w += w * eaB[i].w;
                }
            }
        }
    }

    // expand A_h through We1 (pair-local). Lane pbit|(k>>3) holds feature k
    // (component k&7 of its A2a/A2b).
    float ex0 = 0.f, ex1 = 0.f, ex2 = 0.f, ex3 = 0.f;
    float ex4 = 0.f, ex5 = 0.f, ex6 = 0.f, ex7 = 0.f;
#pragma unroll
    for (int k = 0; k < 16; ++k) {
        float comp = (k & 7) == 0 ? A2a.x : (k & 7) == 1 ? A2a.y :
                     (k & 7) == 2 ? A2a.z : (k & 7) == 3 ? A2a.w :
                     (k & 7) == 4 ? A2b.x : (k & 7) == 5 ? A2b.y :
                     (k & 7) == 6 ? A2b.z : A2b.w;
        float ak = __shfl(comp, pbit | (k >> 3), 64);
        const float* wp = We1 + k * 128 + c0;
        float4 w4a = *(const float4*)(wp);
        float4 w4b = *(const float4*)(wp + 4);
        ex0 += ak * w4a.x; ex1 += ak * w4a.y; ex2 += ak * w4a.z; ex3 += ak * w4a.w;
        ex4 += ak * w4b.x; ex5 += ak * w4b.y; ex6 += ak * w4b.z; ex7 += ak * w4b.w;
    }
    float inv = 1.f / (lden + 1e-16f);
    float o0 = (acA.x + ex0) * inv + sk0.x;
    float o1 = (acA.y + ex1) * inv + sk0.y;
    float o2 = (acA.z + ex2) * inv + sk1.x;
    float o3 = (acA.w + ex3) * inv + sk1.y;
    float o4 = (acB.x + ex4) * inv + sk2.x;
    float o5 = (acB.y + ex5) * inv + sk2.y;
    float o6 = (acB.z + ex6) * inv + sk3.x;
    float o7 = (acB.w + ex7) * inv + sk3.y;
    o0 = o0 > 0.f ? o0 : 0.01f * o0;
    o1 = o1 > 0.f ? o1 : 0.01f * o1;
    o2 = o2 > 0.f ? o2 : 0.01f * o2;
    o3 = o3 > 0.f ? o3 : 0.01f * o3;
    o4 = o4 > 0.f ? o4 : 0.01f * o4;
    o5 = o5 > 0.f ? o5 : 0.01f * o5;
    o6 = o6 > 0.f ? o6 : 0.01f * o6;
    o7 = o7 > 0.f ? o7 : 0.01f * o7;
    uint4 pk;
    pk.x = (unsigned)f2bf(o0) | ((unsigned)f2bf(o1) << 16);
    pk.y = (unsigned)f2bf(o2) | ((unsigned)f2bf(o3) << 16);
    pk.z = (unsigned)f2bf(o4) | ((unsigned)f2bf(o5) << 16);
    pk.w = (unsigned)f2bf(o6) | ((unsigned)f2bf(o7) << 16);
    *(uint4*)(h1 + (size_t)node * 128 + c0) = pk;
}

// Layer 2: H=1, C=128. One node per 16-lane quarter; 16-lane dot per edge
// (4 shfl_xor); lanes 0..3 of the quarter hold the chunk's scores. r10 winner.
__global__ __launch_bounds__(256) void fused2_node(
    const unsigned short* __restrict__ P, const float* __restrict__ qWe,
    const float* __restrict__ ea, const float* __restrict__ We2,
    const int2* __restrict__ csr, const int* __restrict__ rowptr,
    float* __restrict__ out, int N)
{
    const int lane = threadIdx.x & 63;
    const int node = blockIdx.x * 16 + (threadIdx.x >> 4);
    if (node >= N) return;
    const int l16 = lane & 15;
    const int qbit = lane & 48;
    const int c0 = l16 * 8;

    const int beg = rowptr[node];
    const int deg = rowptr[node + 1] - beg;

    uint4 su = *(const uint4*)(P + (size_t)node * 512 + 384 + c0);
    float2 sk0 = bf2(su.x), sk1 = bf2(su.y), sk2 = bf2(su.z), sk3 = bf2(su.w);
    float* outp = out + (size_t)node * 128 + c0;
    if (deg == 0) {
        *(float4*)outp = make_float4(sk0.x, sk0.y, sk1.x, sk1.y);
        *(float4*)(outp + 4) = make_float4(sk2.x, sk2.y, sk3.x, sk3.y);
        return;
    }

    uint4 qu = *(const uint4*)(P + (size_t)node * 512 + 256 + c0);
    float2 q0 = bf2(qu.x), q1 = bf2(qu.y), q2 = bf2(qu.z), q3 = bf2(qu.w);
    float qw = qWe[(size_t)node * 128 + l16];

    float4 acA = make_float4(0.f, 0.f, 0.f, 0.f);
    float4 acB = make_float4(0.f, 0.f, 0.f, 0.f);
    float accA = 0.f;
    float m = -INFINITY, lden = 0.f;

    int2 se = make_int2(0, 0);
    if (l16 < deg) se = csr[beg + l16];

    for (int blk = 0; blk < deg; blk += 16) {
        if (blk) se = (blk + l16 < deg) ? csr[beg + blk + l16] : make_int2(0, 0);
        const int bcnt = min(16, deg - blk);
        for (int cb = 0; cb < bcnt; cb += 4) {
            const int lim = min(4, bcnt - cb);
            uint4 kva[4], kvb[4]; float eav[4];
            // ---- gather phase ----
#pragma unroll
            for (int i = 0; i < 4; ++i) {
                if (i < lim) {
                    int jc = min(cb + i, bcnt - 1);
                    int sb = __shfl(se.x, qbit | jc, 64);
                    int eb = __shfl(se.y, qbit | jc, 64);
                    const unsigned short* kp = P + (size_t)sb * 512 + l16 * 16;
                    kva[i] = *(const uint4*)(kp);
                    kvb[i] = *(const uint4*)(kp + 8);
                    eav[i] = ea[(size_t)eb * 16 + l16];
                }
            }
            // ---- score phase (16-lane dot within quarter) ----
            float my_s = -INFINITY;
#pragma unroll
            for (int i = 0; i < 4; ++i) {
                if (i < lim) {
                    float2 ka = bf2(kva[i].x), kb = bf2(kva[i].z);
                    float2 kc = bf2(kvb[i].x), kd = bf2(kvb[i].z);
                    float p = q0.x * ka.x + q0.y * ka.y + q1.x * kb.x + q1.y * kb.y
                            + q2.x * kc.x + q2.y * kc.y + q3.x * kd.x + q3.y * kd.y
                            + qw * eav[i];
                    p += __shfl_xor(p, 1, 64);
                    p += __shfl_xor(p, 2, 64);
                    p += __shfl_xor(p, 4, 64);
                    p += __shfl_xor(p, 8, 64);     // quarter-wide reduction
                    if (l16 == i) my_s = p * 0.08838834764831845f;  // 1/sqrt(128)
                }
            }
            // ---- online softmax (quarter-local) ----
            float cm = my_s;
#pragma unroll
            for (int mk = 1; mk < 16; mk <<= 1) cm = fmaxf(cm, __shfl_xor(cm, mk, 64));
            float m_new = fmaxf(m, cm);
            float scale = __expf(m - m_new);
            float ew = __expf(my_s - m_new);   // non-slot: 0
            float ds = ew;
#pragma unroll
            for (int mk = 1; mk < 16; mk <<= 1) ds += __shfl_xor(ds, mk, 64);
            lden = lden * scale + ds;
            acA.x *= scale; acA.y *= scale; acA.z *= scale; acA.w *= scale;
            acB.x *= scale; acB.y *= scale; acB.z *= scale; acB.w *= scale;
            accA *= scale;
            m = m_new;
            // ---- accumulate ----
#pragma unroll
            for (int i = 0; i < 4; ++i) {
                if (i < lim) {
                    float w = __shfl(ew, qbit | i, 64);
                    float2 va = bf2(kva[i].y), vb = bf2(kva[i].w);
                    float2 vc = bf2(kvb[i].y), vd = bf2(kvb[i].w);
                    acA.x += w * va.x; acA.y += w * va.y;
                    acA.z += w * vb.x; acA.w += w * vb.y;
                    acB.x += w * vc.x; acB.y += w * vc.y;
                    acB.z += w * vd.x; acB.w += w * vd.y;
                    accA += w * eav[i];
                }
            }
        }
    }

    float ex0 = 0.f, ex1 = 0.f, ex2 = 0.f, ex3 = 0.f;
    float ex4 = 0.f, ex5 = 0.f, ex6 = 0.f, ex7 = 0.f;
#pragma unroll
    for (int k = 0; k < 16; ++k) {
        float ak = __shfl(accA, qbit | k, 64);   // lane qbit+k holds feature k
        const float* wp = We2 + k * 128 + c0;
        float4 w4a = *(const float4*)(wp);
        float4 w4b = *(const float4*)(wp + 4);
        ex0 += ak * w4a.x; ex1 += ak * w4a.y; ex2 += ak * w4a.z; ex3 += ak * w4a.w;
        ex4 += ak * w4b.x; ex5 += ak * w4b.y; ex6 += ak * w4b.z; ex7 += ak * w4b.w;
    }
    float inv = 1.f / (lden + 1e-16f);
    float4 oA, oB;
    oA.x = (acA.x + ex0) * inv + sk0.x;
    oA.y = (acA.y + ex1) * inv + sk0.y;
    oA.z = (acA.z + ex2) * inv + sk1.x;
    oA.w = (acA.w + ex3) * inv + sk1.y;
    oB.x = (acB.x + ex4) * inv + sk2.x;
    oB.y = (acB.y + ex5) * inv + sk2.y;
    oB.z = (acB.z + ex6) * inv + sk3.x;
    oB.w = (acB.w + ex7) * inv + sk3.y;
    *(float4*)outp = oA;
    *(float4*)(outp + 4) = oB;
}

// ---------------- launch ----------------
extern "C" void kernel_launch(void* const* d_in, const int* in_sizes, int n_in,
                              void* d_out, int out_size, void* d_ws, size_t ws_size,
                              hipStream_t stream)
{
    const float* x  = (const float*)d_in[0];
    const int*   ei = (const int*)d_in[1];
    const float* ea = (const float*)d_in[2];
    const float *Wq1 = (const float*)d_in[3],  *bq1 = (const float*)d_in[4];
    const float *Wk1 = (const float*)d_in[5],  *bk1 = (const float*)d_in[6];
    const float *Wv1 = (const float*)d_in[7],  *bv1 = (const float*)d_in[8];
    const float *We1 = (const float*)d_in[9],  *be1 = (const float*)d_in[10];
    const float *Ws1 = (const float*)d_in[11], *bs1 = (const float*)d_in[12];
    const float *Wq2 = (const float*)d_in[13], *bq2 = (const float*)d_in[14];
    const float *Wk2 = (const float*)d_in[15], *bk2 = (const float*)d_in[16];
    const float *Wv2 = (const float*)d_in[17], *bv2 = (const float*)d_in[18];
    const float *We2 = (const float*)d_in[19], *be2 = (const float*)d_in[20];
    const float *Ws2 = (const float*)d_in[21], *bs2 = (const float*)d_in[22];

    const int N = in_sizes[0] / 128;
    const int E = in_sizes[1] / 2;

    char* ws = (char*)d_ws;
    size_t off = 0;
    auto alloc = [&](size_t bytes) -> void* {
        void* p = ws + off;
        off = (off + bytes + 255) & ~(size_t)255;
        return p;
    };
    unsigned short* xb  = (unsigned short*)alloc((size_t)N * 128 * 2);
    unsigned short* P   = (unsigned short*)alloc((size_t)N * 512 * 2);  // bf16 [kv-interleave | q | s]
    unsigned short* h1b = (unsigned short*)alloc((size_t)N * 128 * 2);
    unsigned short* Wt1 = (unsigned short*)alloc((size_t)640 * 128 * 2);
    unsigned short* Wt2 = (unsigned short*)alloc((size_t)640 * 128 * 2);
    float* bias1 = (float*)alloc(640 * 4);
    float* bias2 = (float*)alloc(640 * 4);
    float* qWe   = (float*)alloc((size_t)N * 128 * 4);
    int*  deg    = (int*)alloc((size_t)N * 4);
    int*  rowptr = (int*)alloc((size_t)(N + 1) * 4);
    int*  cursor = (int*)alloc((size_t)N * 4);
    int*  partial= (int*)alloc(256 * 4);
    int2* csr    = (int2*)alloc((size_t)E * 8);

    dim3 gemm_grid1((N + 127) / 128, 10);
    dim3 gemm_grid2((N + 127) / 128, 9);   // layer-2 qWe needs only cols [512,528)
    const int tn = N * 128;
    const int node_blocks = (N + 15) / 16;   // 16 nodes (16 quarter-waves) per 256-thread block
    const int prep_blocks = (640 * 128 + 255) / 256;
    const int scan_blocks = (N + 255) / 256; // <=256 required (N<=65536)

    // ---- prep (independent of everything else) ----
    convert_x<<<(tn + 255) / 256, 256, 0, stream>>>(x, xb, tn);
    prep_w<<<prep_blocks, 256, 0, stream>>>(Wq1, bq1, Wk1, bk1, Wv1, bv1, be1, Ws1, bs1, We1, 8, Wt1, bias1);
    prep_w<<<prep_blocks, 256, 0, stream>>>(Wq2, bq2, Wk2, bk2, Wv2, bv2, be2, Ws2, bs2, We2, 1, Wt2, bias2);

    // ---- CSR build (shared by both layers) ----
    hipMemsetAsync(deg, 0, (size_t)N * 4, stream);
    hipMemsetAsync(partial, 0, 256 * 4, stream);
    degree_kernel<<<(E + 255) / 256, 256, 0, stream>>>(ei, deg, E);
    scan_part1<<<scan_blocks, 256, 0, stream>>>(deg, partial, N);
    scan_part2<<<1, 256, 0, stream>>>(partial);
    scan_part3<<<scan_blocks, 256, 0, stream>>>(deg, partial, rowptr, cursor, N);
    scatter_kernel<<<(E + 255) / 256, 256, 0, stream>>>(ei, cursor, csr, E);

    // ---- layer 1 (H=8, C=16, concat) ----
    gemm_bf16<<<gemm_grid1, 256, 0, stream>>>(xb, N, Wt1, bias1, P, qWe);
    fused1_node<<<node_blocks, 256, 0, stream>>>(P, qWe, ea, We1, csr, rowptr, h1b, N);

    // ---- layer 2 (H=1, C=128, mean==identity) ----
    gemm_bf16<<<gemm_grid2, 256, 0, stream>>>(h1b, N, Wt2, bias2, P, qWe);
    fused2_node<<<node_blocks, 256, 0, stream>>>(P, qWe, ea, We2, csr, rowptr, (float*)d_out, N);
}

// Round 14
// 450.267 us; speedup vs baseline: 1.0997x; 1.0544x over previous
//
#include <hip/hip_runtime.h>
#include <math.h>

typedef __bf16 bf16x8 __attribute__((ext_vector_type(8)));
typedef float f32x4 __attribute__((ext_vector_type(4)));

// ---------------- bf16 helpers ----------------
__device__ __forceinline__ unsigned short f2bf(float f) {
    unsigned u = __float_as_uint(f);
    return (unsigned short)((u + 0x7fffu + ((u >> 16) & 1u)) >> 16);
}
__device__ __forceinline__ float2 bf2(unsigned u) {
    float2 r;
    r.x = __uint_as_float(u << 16);
    r.y = __uint_as_float(u & 0xffff0000u);
    return r;
}

// ---------------- prep weight body (shared by both layers) ----------------
// Output-column order == final P position (kv interleave baked in):
//   p in [0,256): cc = 2*(p>>2)+(p&1), W = (p&2)?Wv:Wk, +be folded.
//   [256,384)=q (Wq,bq); [384,512)=s (Ws,bs);
//   [512,640): qWe fused cols: Wt[c][d] = sum_i Wq[d,h*C+i]*We[kk*128+h*C+i].
__device__ __forceinline__ void prep_one(
    int g, int H,
    const float* __restrict__ Wq, const float* __restrict__ bq,
    const float* __restrict__ Wk, const float* __restrict__ bk,
    const float* __restrict__ Wv, const float* __restrict__ bv,
    const float* __restrict__ be,
    const float* __restrict__ Ws, const float* __restrict__ bs,
    const float* __restrict__ We,
    unsigned short* __restrict__ Wt, float* __restrict__ bias)
{
    const int C = 128 / H;
    if (g < 640) {
        int p = g;
        float b;
        if (p < 256) {
            int cc = 2 * (p >> 2) + (p & 1);
            b = ((p & 2) ? bv[cc] : bk[cc]) + be[cc];
        }
        else if (p < 384) b = bq[p - 256];
        else if (p < 512) b = bs[p - 384];
        else {
            int c2 = p - 512, h = c2 >> 4, kk = c2 & 15;
            b = 0.f;
            if (h < H) for (int i = 0; i < C; ++i) b += bq[h * C + i] * We[kk * 128 + h * C + i];
        }
        bias[p] = b;
    }
    int p = g >> 7, d = g & 127;
    float w;
    if (p < 256) {
        int cc = 2 * (p >> 2) + (p & 1);
        w = (p & 2) ? Wv[d * 128 + cc] : Wk[d * 128 + cc];
    } else if (p < 384) {
        w = Wq[d * 128 + (p - 256)];
    } else if (p < 512) {
        w = Ws[d * 128 + (p - 384)];
    } else {
        int c2 = p - 512, h = c2 >> 4, kk = c2 & 15;
        w = 0.f;
        if (h < H) for (int i = 0; i < C; ++i) w += Wq[d * 128 + h * C + i] * We[kk * 128 + h * C + i];
    }
    Wt[(size_t)p * 128 + d] = f2bf(w);
}

// ---------------- ROUND 14: fused prep mega-kernel ----------------
// convert_x + prep_w(layer1) + prep_w(layer2) + degree are mutually
// independent -> one flat-indexed launch (segments by global thread id).
// Cuts the serial dispatch chain 14 -> 10 launches. deg memset ordering is
// guaranteed by stream order (memset precedes this kernel).
__global__ __launch_bounds__(256) void prep_all(
    const float* __restrict__ x, unsigned short* __restrict__ xb, int tn,
    const int* __restrict__ ei, int* __restrict__ deg, int E,
    const float* __restrict__ Wq1, const float* __restrict__ bq1,
    const float* __restrict__ Wk1, const float* __restrict__ bk1,
    const float* __restrict__ Wv1, const float* __restrict__ bv1,
    const float* __restrict__ be1,
    const float* __restrict__ Ws1, const float* __restrict__ bs1,
    const float* __restrict__ We1,
    unsigned short* __restrict__ Wt1, float* __restrict__ bias1,
    const float* __restrict__ Wq2, const float* __restrict__ bq2,
    const float* __restrict__ Wk2, const float* __restrict__ bk2,
    const float* __restrict__ Wv2, const float* __restrict__ bv2,
    const float* __restrict__ be2,
    const float* __restrict__ Ws2, const float* __restrict__ bs2,
    const float* __restrict__ We2,
    unsigned short* __restrict__ Wt2, float* __restrict__ bias2)
{
    const int SEG = 640 * 128;
    int g = blockIdx.x * 256 + threadIdx.x;
    if (g < tn) { xb[g] = f2bf(x[g]); return; }
    g -= tn;
    if (g < SEG) {
        prep_one(g, 8, Wq1, bq1, Wk1, bk1, Wv1, bv1, be1, Ws1, bs1, We1, Wt1, bias1);
        return;
    }
    g -= SEG;
    if (g < SEG) {
        prep_one(g, 1, Wq2, bq2, Wk2, bk2, Wv2, bv2, be2, Ws2, bs2, We2, Wt2, bias2);
        return;
    }
    g -= SEG;
    if (g < E) atomicAdd(&deg[ei[E + g]], 1);
}

// ---------------- MFMA bf16 GEMM: [P | qWe] = Xb[m,128] @ Wt + bias ----------------
// r13: 2 row-tiles (32 rows) per wave; B tile (64 cols x 128 k, 16 KB) in
// LDS; C-frag: col=lane&15, row=(lane>>4)*4+reg [m89/m91].
__global__ __launch_bounds__(256) void gemm_bf16(
    const unsigned short* __restrict__ Xb, int M,
    const unsigned short* __restrict__ Wt, const float* __restrict__ bias,
    unsigned short* __restrict__ P, float* __restrict__ qWe)
{
    __shared__ unsigned short Bs[64][136];
    __shared__ unsigned short tile[4][32][64];
    const int wv = threadIdx.x >> 6, lane = threadIdx.x & 63;
    const int row0 = blockIdx.x * 128 + wv * 32;    // 32 rows per wave
    const int n0 = blockIdx.y * 64;                 // [0,640)
    const int quad = lane >> 4, l16 = lane & 15;

    {   // stage Wt column-tile into LDS: 1024 x uint4, coalesced
        const uint4* gsrc = (const uint4*)(Wt + (size_t)n0 * 128);
#pragma unroll
        for (int u = 0; u < 4; ++u) {
            int v = threadIdx.x + u * 256;
            int col = v >> 4, k8 = v & 15;
            *(uint4*)(&Bs[col][k8 * 8]) = gsrc[v];
        }
    }
    __syncthreads();

    f32x4 acc[2][4] = {};
    const int kb = quad * 8;
    bf16x8 a[2][4];
#pragma unroll
    for (int r2 = 0; r2 < 2; ++r2) {
        int mrow = row0 + r2 * 16 + l16; if (mrow >= M) mrow = M - 1;  // clamp; stores guarded
#pragma unroll
        for (int kk = 0; kk < 4; ++kk)
            a[r2][kk] = *(const bf16x8*)(Xb + (size_t)mrow * 128 + kk * 32 + kb);
    }
#pragma unroll
    for (int kk = 0; kk < 4; ++kk) {
#pragma unroll
        for (int f = 0; f < 4; ++f) {
            bf16x8 b = *(const bf16x8*)(&Bs[f * 16 + l16][kk * 32 + kb]);
            acc[0][f] = __builtin_amdgcn_mfma_f32_16x16x32_bf16(a[0][kk], b, acc[0][f], 0, 0, 0);
            acc[1][f] = __builtin_amdgcn_mfma_f32_16x16x32_bf16(a[1][kk], b, acc[1][f], 0, 0, 0);
        }
    }
    if (n0 < 512) {
#pragma unroll
        for (int r2 = 0; r2 < 2; ++r2) {
#pragma unroll
            for (int f = 0; f < 4; ++f) {
                float bs = bias[n0 + f * 16 + l16];
#pragma unroll
                for (int r = 0; r < 4; ++r) {
                    int row = quad * 4 + r;
                    int col = f * 16 + l16;
                    tile[wv][r2 * 16 + row][col ^ ((row & 3) << 4)] = f2bf(acc[r2][f][r] + bs);
                }
            }
        }
        __syncthreads();
        int row = lane >> 2, seg = lane & 3;
#pragma unroll
        for (int rr = 0; rr < 2; ++rr) {
            int m = row0 + rr * 16 + row;
            if (m < M) {
                const uint4* src = (const uint4*)&tile[wv][rr * 16 + row][(seg ^ (row & 3)) << 4];
                uint4* dst = (uint4*)(P + (size_t)m * 512 + n0 + seg * 16);
                dst[0] = src[0];
                dst[1] = src[1];
            }
        }
    } else {
#pragma unroll
        for (int r2 = 0; r2 < 2; ++r2) {
#pragma unroll
            for (int f = 0; f < 4; ++f) {
                int c = n0 + f * 16 + l16;
                float bs = bias[c];
#pragma unroll
                for (int r = 0; r < 4; ++r) {
                    int m = row0 + r2 * 16 + quad * 4 + r;
                    if (m < M) qWe[(size_t)m * 128 + (c - 512)] = acc[r2][f][r] + bs;
                }
            }
        }
    }
}

// Block-parallel 3-phase prefix sum (r9 win: replaced 122us single-block scan).
__global__ __launch_bounds__(256) void scan_part1(
    const int* __restrict__ deg, int* __restrict__ partial, int N)
{
    __shared__ int s[256];
    const int t = threadIdx.x;
    const int g = blockIdx.x * 256 + t;
    int v = (g < N) ? deg[g] : 0;
    s[t] = v;
    __syncthreads();
    for (int ofs = 128; ofs > 0; ofs >>= 1) {
        if (t < ofs) s[t] += s[t + ofs];
        __syncthreads();
    }
    if (t == 0) partial[blockIdx.x] = s[0];
}

__global__ __launch_bounds__(256) void scan_part2(
    int* __restrict__ partial, int nblk)   // entries >= nblk treated as 0 (no memset)
{
    __shared__ int s[256];
    const int t = threadIdx.x;
    int v = (t < nblk) ? partial[t] : 0;
    s[t] = v;
    __syncthreads();
    for (int ofs = 1; ofs < 256; ofs <<= 1) {
        int u = (t >= ofs) ? s[t - ofs] : 0;
        __syncthreads();
        s[t] += u;
        __syncthreads();
    }
    partial[t] = s[t] - v;   // exclusive
}

__global__ __launch_bounds__(256) void scan_part3(
    const int* __restrict__ deg, const int* __restrict__ offs,
    int* __restrict__ rowptr, int* __restrict__ cursor, int N)
{
    __shared__ int s[256];
    const int t = threadIdx.x;
    const int g = blockIdx.x * 256 + t;
    int v = (g < N) ? deg[g] : 0;
    s[t] = v;
    __syncthreads();
    for (int ofs = 1; ofs < 256; ofs <<= 1) {
        int u = (t >= ofs) ? s[t - ofs] : 0;
        __syncthreads();
        s[t] += u;
        __syncthreads();
    }
    const int incl = s[t];
    const int base = offs[blockIdx.x];
    if (g < N) {
        cursor[g] = base + incl - v;      // exclusive prefix
        rowptr[g + 1] = base + incl;      // inclusive prefix
    }
    if (g == 0) rowptr[0] = 0;
}

__global__ __launch_bounds__(256) void scatter_kernel(
    const int* __restrict__ ei, int* __restrict__ cursor,
    int2* __restrict__ csr, int E)
{
    int e = blockIdx.x * blockDim.x + threadIdx.x;
    if (e < E) {
        int pos = atomicAdd(&cursor[ei[E + e]], 1);
        csr[pos] = make_int2(ei[e], e);   // (src, edge id)
    }
}

// ---------------- fused score + online-softmax + aggregation ----------------
// r10 WINNER (byte-identical): one node per 16-lane quarter-wave, chunk=4.
// r11 (chunk=8, VGPR 108) and r12 (LDS CSR staging) both regressed — this
// is the measured optimum of the geometry/chunk/staging space at 90 us.
__global__ __launch_bounds__(256) void fused1_node(
    const unsigned short* __restrict__ P, const float* __restrict__ qWe,
    const float* __restrict__ ea, const float* __restrict__ We1,
    const int2* __restrict__ csr, const int* __restrict__ rowptr,
    unsigned short* __restrict__ h1, int N)
{
    const int lane = threadIdx.x & 63;
    const int node = blockIdx.x * 16 + (threadIdx.x >> 4);   // one node per quarter
    if (node >= N) return;
    const int l16 = lane & 15;
    const int qbit = lane & 48;       // quarter base (shfl indices)
    const int pbit = lane & 62;       // head-pair base (2 lanes per head)
    const int odd  = lane & 1;        // which ea-feature half this lane owns
    const int c0 = l16 * 8;           // 8 channels per lane

    const int beg = rowptr[node];
    const int deg = rowptr[node + 1] - beg;

    uint4 su = *(const uint4*)(P + (size_t)node * 512 + 384 + c0);
    float2 sk0 = bf2(su.x), sk1 = bf2(su.y), sk2 = bf2(su.z), sk3 = bf2(su.w);
    if (deg == 0) {
        float o0 = sk0.x > 0.f ? sk0.x : 0.01f * sk0.x;
        float o1 = sk0.y > 0.f ? sk0.y : 0.01f * sk0.y;
        float o2 = sk1.x > 0.f ? sk1.x : 0.01f * sk1.x;
        float o3 = sk1.y > 0.f ? sk1.y : 0.01f * sk1.y;
        float o4 = sk2.x > 0.f ? sk2.x : 0.01f * sk2.x;
        float o5 = sk2.y > 0.f ? sk2.y : 0.01f * sk2.y;
        float o6 = sk3.x > 0.f ? sk3.x : 0.01f * sk3.x;
        float o7 = sk3.y > 0.f ? sk3.y : 0.01f * sk3.y;
        uint4 pk;
        pk.x = (unsigned)f2bf(o0) | ((unsigned)f2bf(o1) << 16);
        pk.y = (unsigned)f2bf(o2) | ((unsigned)f2bf(o3) << 16);
        pk.z = (unsigned)f2bf(o4) | ((unsigned)f2bf(o5) << 16);
        pk.w = (unsigned)f2bf(o6) | ((unsigned)f2bf(o7) << 16);
        *(uint4*)(h1 + (size_t)node * 128 + c0) = pk;
        return;
    }

    uint4 qu = *(const uint4*)(P + (size_t)node * 512 + 256 + c0);
    float2 q0 = bf2(qu.x), q1 = bf2(qu.y), q2 = bf2(qu.z), q3 = bf2(qu.w);
    float4 qwA = *(const float4*)(qWe + (size_t)node * 128 + c0);
    float4 qwB = *(const float4*)(qWe + (size_t)node * 128 + c0 + 4);

    float4 acA = make_float4(0.f, 0.f, 0.f, 0.f);   // v accum ch c0..c0+3
    float4 acB = make_float4(0.f, 0.f, 0.f, 0.f);   // v accum ch c0+4..+7
    float4 A2a = make_float4(0.f, 0.f, 0.f, 0.f);   // ea accum kk odd*8..+3
    float4 A2b = make_float4(0.f, 0.f, 0.f, 0.f);   // ea accum kk odd*8+4..+7
    float m = -INFINITY, lden = 0.f;

    int2 se = make_int2(0, 0);
    if (l16 < deg) se = csr[beg + l16];

    for (int blk = 0; blk < deg; blk += 16) {
        if (blk) se = (blk + l16 < deg) ? csr[beg + blk + l16] : make_int2(0, 0);
        const int bcnt = min(16, deg - blk);
        for (int cb = 0; cb < bcnt; cb += 4) {
            const int lim = min(4, bcnt - cb);
            uint4 kva[4], kvb[4]; float4 eaA[4], eaB[4];
            // ---- gather phase: loads only ----
#pragma unroll
            for (int i = 0; i < 4; ++i) {
                if (i < lim) {   // quarter-uniform
                    int jc = min(cb + i, bcnt - 1);
                    int sb = __shfl(se.x, qbit | jc, 64);
                    int eb = __shfl(se.y, qbit | jc, 64);
                    const unsigned short* kp = P + (size_t)sb * 512 + l16 * 16;
                    kva[i] = *(const uint4*)(kp);
                    kvb[i] = *(const uint4*)(kp + 8);
                    const float* ep = ea + (size_t)eb * 16 + odd * 8;
                    eaA[i] = *(const float4*)(ep);
                    eaB[i] = *(const float4*)(ep + 4);
                }
            }
            // ---- score phase: owner lane odd==(i&1), slot i>>1 ----
            float s0 = -INFINITY, s1 = -INFINITY;
#pragma unroll
            for (int i = 0; i < 4; ++i) {
                if (i < lim) {
                    float2 ka = bf2(kva[i].x), kb = bf2(kva[i].z);
                    float2 kc = bf2(kvb[i].x), kd = bf2(kvb[i].z);
                    float p = q0.x * ka.x + q0.y * ka.y + q1.x * kb.x + q1.y * kb.y
                            + q2.x * kc.x + q2.y * kc.y + q3.x * kd.x + q3.y * kd.y
                            + qwA.x * eaA[i].x + qwA.y * eaA[i].y
                            + qwA.z * eaA[i].z + qwA.w * eaA[i].w
                            + qwB.x * eaB[i].x + qwB.y * eaB[i].y
                            + qwB.z * eaB[i].z + qwB.w * eaB[i].w;
                    p += __shfl_xor(p, 1, 64);    // head-pair sum
                    float pv = p * 0.25f;         // 1/sqrt(16)
                    if (odd == (i & 1)) { if (i < 2) s0 = pv; else s1 = pv; }
                }
            }
            // ---- online softmax update (per head; pair-local) ----
            float cm = fmaxf(s0, s1);
            cm = fmaxf(cm, __shfl_xor(cm, 1, 64));
            float m_new = fmaxf(m, cm);
            float scale = __expf(m - m_new);      // first chunk: exp(-inf)=0
            float e0 = __expf(s0 - m_new);        // unassigned slots: 0
            float e1 = __expf(s1 - m_new);
            float ds = e0 + e1;
            ds += __shfl_xor(ds, 1, 64);
            lden = lden * scale + ds;
            acA.x *= scale; acA.y *= scale; acA.z *= scale; acA.w *= scale;
            acB.x *= scale; acB.y *= scale; acB.z *= scale; acB.w *= scale;
            A2a.x *= scale; A2a.y *= scale; A2a.z *= scale; A2a.w *= scale;
            A2b.x *= scale; A2b.y *= scale; A2b.z *= scale; A2b.w *= scale;
            m = m_new;
            // ---- accumulate phase ----
#pragma unroll
            for (int i = 0; i < 4; ++i) {
                if (i < lim) {
                    float w = __shfl((i < 2) ? e0 : e1, pbit | (i & 1), 64);
                    float2 va = bf2(kva[i].y), vb = bf2(kva[i].w);
                    float2 vc = bf2(kvb[i].y), vd = bf2(kvb[i].w);
                    acA.x += w * va.x; acA.y += w * va.y;
                    acA.z += w * vb.x; acA.w += w * vb.y;
                    acB.x += w * vc.x; acB.y += w * vc.y;
                    acB.z += w * vd.x; acB.w += w * vd.y;
                    A2a.x += w * eaA[i].x; A2a.y += w * eaA[i].y;
                    A2a.z += w * eaA[i].z; A2a.w += w * eaA[i].w;
                    A2b.x += w * eaB[i].x; A2b.y += w * eaB[i].y;
                    A2b.z += w * eaB[i].z; A2b.w += w * eaB[i].w;
                }
            }
        }
    }

    // expand A_h through We1 (pair-local). Lane pbit|(k>>3) holds feature k
    // (component k&7 of its A2a/A2b).
    float ex0 = 0.f, ex1 = 0.f, ex2 = 0.f, ex3 = 0.f;
    float ex4 = 0.f, ex5 = 0.f, ex6 = 0.f, ex7 = 0.f;
#pragma unroll
    for (int k = 0; k < 16; ++k) {
        float comp = (k & 7) == 0 ? A2a.x : (k & 7) == 1 ? A2a.y :
                     (k & 7) == 2 ? A2a.z : (k & 7) == 3 ? A2a.w :
                     (k & 7) == 4 ? A2b.x : (k & 7) == 5 ? A2b.y :
                     (k & 7) == 6 ? A2b.z : A2b.w;
        float ak = __shfl(comp, pbit | (k >> 3), 64);
        const float* wp = We1 + k * 128 + c0;
        float4 w4a = *(const float4*)(wp);
        float4 w4b = *(const float4*)(wp + 4);
        ex0 += ak * w4a.x; ex1 += ak * w4a.y; ex2 += ak * w4a.z; ex3 += ak * w4a.w;
        ex4 += ak * w4b.x; ex5 += ak * w4b.y; ex6 += ak * w4b.z; ex7 += ak * w4b.w;
    }
    float inv = 1.f / (lden + 1e-16f);
    float o0 = (acA.x + ex0) * inv + sk0.x;
    float o1 = (acA.y + ex1) * inv + sk0.y;
    float o2 = (acA.z + ex2) * inv + sk1.x;
    float o3 = (acA.w + ex3) * inv + sk1.y;
    float o4 = (acB.x + ex4) * inv + sk2.x;
    float o5 = (acB.y + ex5) * inv + sk2.y;
    float o6 = (acB.z + ex6) * inv + sk3.x;
    float o7 = (acB.w + ex7) * inv + sk3.y;
    o0 = o0 > 0.f ? o0 : 0.01f * o0;
    o1 = o1 > 0.f ? o1 : 0.01f * o1;
    o2 = o2 > 0.f ? o2 : 0.01f * o2;
    o3 = o3 > 0.f ? o3 : 0.01f * o3;
    o4 = o4 > 0.f ? o4 : 0.01f * o4;
    o5 = o5 > 0.f ? o5 : 0.01f * o5;
    o6 = o6 > 0.f ? o6 : 0.01f * o6;
    o7 = o7 > 0.f ? o7 : 0.01f * o7;
    uint4 pk;
    pk.x = (unsigned)f2bf(o0) | ((unsigned)f2bf(o1) << 16);
    pk.y = (unsigned)f2bf(o2) | ((unsigned)f2bf(o3) << 16);
    pk.z = (unsigned)f2bf(o4) | ((unsigned)f2bf(o5) << 16);
    pk.w = (unsigned)f2bf(o6) | ((unsigned)f2bf(o7) << 16);
    *(uint4*)(h1 + (size_t)node * 128 + c0) = pk;
}

// Layer 2: H=1, C=128. One node per 16-lane quarter; 16-lane dot per edge
// (4 shfl_xor); lanes 0..3 of the quarter hold the chunk's scores. r10 winner.
__global__ __launch_bounds__(256) void fused2_node(
    const unsigned short* __restrict__ P, const float* __restrict__ qWe,
    const float* __restrict__ ea, const float* __restrict__ We2,
    const int2* __restrict__ csr, const int* __restrict__ rowptr,
    float* __restrict__ out, int N)
{
    const int lane = threadIdx.x & 63;
    const int node = blockIdx.x * 16 + (threadIdx.x >> 4);
    if (node >= N) return;
    const int l16 = lane & 15;
    const int qbit = lane & 48;
    const int c0 = l16 * 8;

    const int beg = rowptr[node];
    const int deg = rowptr[node + 1] - beg;

    uint4 su = *(const uint4*)(P + (size_t)node * 512 + 384 + c0);
    float2 sk0 = bf2(su.x), sk1 = bf2(su.y), sk2 = bf2(su.z), sk3 = bf2(su.w);
    float* outp = out + (size_t)node * 128 + c0;
    if (deg == 0) {
        *(float4*)outp = make_float4(sk0.x, sk0.y, sk1.x, sk1.y);
        *(float4*)(outp + 4) = make_float4(sk2.x, sk2.y, sk3.x, sk3.y);
        return;
    }

    uint4 qu = *(const uint4*)(P + (size_t)node * 512 + 256 + c0);
    float2 q0 = bf2(qu.x), q1 = bf2(qu.y), q2 = bf2(qu.z), q3 = bf2(qu.w);
    float qw = qWe[(size_t)node * 128 + l16];

    float4 acA = make_float4(0.f, 0.f, 0.f, 0.f);
    float4 acB = make_float4(0.f, 0.f, 0.f, 0.f);
    float accA = 0.f;
    float m = -INFINITY, lden = 0.f;

    int2 se = make_int2(0, 0);
    if (l16 < deg) se = csr[beg + l16];

    for (int blk = 0; blk < deg; blk += 16) {
        if (blk) se = (blk + l16 < deg) ? csr[beg + blk + l16] : make_int2(0, 0);
        const int bcnt = min(16, deg - blk);
        for (int cb = 0; cb < bcnt; cb += 4) {
            const int lim = min(4, bcnt - cb);
            uint4 kva[4], kvb[4]; float eav[4];
            // ---- gather phase ----
#pragma unroll
            for (int i = 0; i < 4; ++i) {
                if (i < lim) {
                    int jc = min(cb + i, bcnt - 1);
                    int sb = __shfl(se.x, qbit | jc, 64);
                    int eb = __shfl(se.y, qbit | jc, 64);
                    const unsigned short* kp = P + (size_t)sb * 512 + l16 * 16;
                    kva[i] = *(const uint4*)(kp);
                    kvb[i] = *(const uint4*)(kp + 8);
                    eav[i] = ea[(size_t)eb * 16 + l16];
                }
            }
            // ---- score phase (16-lane dot within quarter) ----
            float my_s = -INFINITY;
#pragma unroll
            for (int i = 0; i < 4; ++i) {
                if (i < lim) {
                    float2 ka = bf2(kva[i].x), kb = bf2(kva[i].z);
                    float2 kc = bf2(kvb[i].x), kd = bf2(kvb[i].z);
                    float p = q0.x * ka.x + q0.y * ka.y + q1.x * kb.x + q1.y * kb.y
                            + q2.x * kc.x + q2.y * kc.y + q3.x * kd.x + q3.y * kd.y
                            + qw * eav[i];
                    p += __shfl_xor(p, 1, 64);
                    p += __shfl_xor(p, 2, 64);
                    p += __shfl_xor(p, 4, 64);
                    p += __shfl_xor(p, 8, 64);     // quarter-wide reduction
                    if (l16 == i) my_s = p * 0.08838834764831845f;  // 1/sqrt(128)
                }
            }
            // ---- online softmax (quarter-local) ----
            float cm = my_s;
#pragma unroll
            for (int mk = 1; mk < 16; mk <<= 1) cm = fmaxf(cm, __shfl_xor(cm, mk, 64));
            float m_new = fmaxf(m, cm);
            float scale = __expf(m - m_new);
            float ew = __expf(my_s - m_new);   // non-slot: 0
            float ds = ew;
#pragma unroll
            for (int mk = 1; mk < 16; mk <<= 1) ds += __shfl_xor(ds, mk, 64);
            lden = lden * scale + ds;
            acA.x *= scale; acA.y *= scale; acA.z *= scale; acA.w *= scale;
            acB.x *= scale; acB.y *= scale; acB.z *= scale; acB.w *= scale;
            accA *= scale;
            m = m_new;
            // ---- accumulate ----
#pragma unroll
            for (int i = 0; i < 4; ++i) {
                if (i < lim) {
                    float w = __shfl(ew, qbit | i, 64);
                    float2 va = bf2(kva[i].y), vb = bf2(kva[i].w);
                    float2 vc = bf2(kvb[i].y), vd = bf2(kvb[i].w);
                    acA.x += w * va.x; acA.y += w * va.y;
                    acA.z += w * vb.x; acA.w += w * vb.y;
                    acB.x += w * vc.x; acB.y += w * vc.y;
                    acB.z += w * vd.x; acB.w += w * vd.y;
                    accA += w * eav[i];
                }
            }
        }
    }

    float ex0 = 0.f, ex1 = 0.f, ex2 = 0.f, ex3 = 0.f;
    float ex4 = 0.f, ex5 = 0.f, ex6 = 0.f, ex7 = 0.f;
#pragma unroll
    for (int k = 0; k < 16; ++k) {
        float ak = __shfl(accA, qbit | k, 64);   // lane qbit+k holds feature k
        const float* wp = We2 + k * 128 + c0;
        float4 w4a = *(const float4*)(wp);
        float4 w4b = *(const float4*)(wp + 4);
        ex0 += ak * w4a.x; ex1 += ak * w4a.y; ex2 += ak * w4a.z; ex3 += ak * w4a.w;
        ex4 += ak * w4b.x; ex5 += ak * w4b.y; ex6 += ak * w4b.z; ex7 += ak * w4b.w;
    }
    float inv = 1.f / (lden + 1e-16f);
    float4 oA, oB;
    oA.x = (acA.x + ex0) * inv + sk0.x;
    oA.y = (acA.y + ex1) * inv + sk0.y;
    oA.z = (acA.z + ex2) * inv + sk1.x;
    oA.w = (acA.w + ex3) * inv + sk1.y;
    oB.x = (acB.x + ex4) * inv + sk2.x;
    oB.y = (acB.y + ex5) * inv + sk2.y;
    oB.z = (acB.z + ex6) * inv + sk3.x;
    oB.w = (acB.w + ex7) * inv + sk3.y;
    *(float4*)outp = oA;
    *(float4*)(outp + 4) = oB;
}

// ---------------- launch ----------------
extern "C" void kernel_launch(void* const* d_in, const int* in_sizes, int n_in,
                              void* d_out, int out_size, void* d_ws, size_t ws_size,
                              hipStream_t stream)
{
    const float* x  = (const float*)d_in[0];
    const int*   ei = (const int*)d_in[1];
    const float* ea = (const float*)d_in[2];
    const float *Wq1 = (const float*)d_in[3],  *bq1 = (const float*)d_in[4];
    const float *Wk1 = (const float*)d_in[5],  *bk1 = (const float*)d_in[6];
    const float *Wv1 = (const float*)d_in[7],  *bv1 = (const float*)d_in[8];
    const float *We1 = (const float*)d_in[9],  *be1 = (const float*)d_in[10];
    const float *Ws1 = (const float*)d_in[11], *bs1 = (const float*)d_in[12];
    const float *Wq2 = (const float*)d_in[13], *bq2 = (const float*)d_in[14];
    const float *Wk2 = (const float*)d_in[15], *bk2 = (const float*)d_in[16];
    const float *Wv2 = (const float*)d_in[17], *bv2 = (const float*)d_in[18];
    const float *We2 = (const float*)d_in[19], *be2 = (const float*)d_in[20];
    const float *Ws2 = (const float*)d_in[21], *bs2 = (const float*)d_in[22];

    const int N = in_sizes[0] / 128;
    const int E = in_sizes[1] / 2;

    char* ws = (char*)d_ws;
    size_t off = 0;
    auto alloc = [&](size_t bytes) -> void* {
        void* p = ws + off;
        off = (off + bytes + 255) & ~(size_t)255;
        return p;
    };
    unsigned short* xb  = (unsigned short*)alloc((size_t)N * 128 * 2);
    unsigned short* P   = (unsigned short*)alloc((size_t)N * 512 * 2);  // bf16 [kv-interleave | q | s]
    unsigned short* h1b = (unsigned short*)alloc((size_t)N * 128 * 2);
    unsigned short* Wt1 = (unsigned short*)alloc((size_t)640 * 128 * 2);
    unsigned short* Wt2 = (unsigned short*)alloc((size_t)640 * 128 * 2);
    float* bias1 = (float*)alloc(640 * 4);
    float* bias2 = (float*)alloc(640 * 4);
    float* qWe   = (float*)alloc((size_t)N * 128 * 4);
    int*  deg    = (int*)alloc((size_t)N * 4);
    int*  rowptr = (int*)alloc((size_t)(N + 1) * 4);
    int*  cursor = (int*)alloc((size_t)N * 4);
    int*  partial= (int*)alloc(256 * 4);
    int2* csr    = (int2*)alloc((size_t)E * 8);

    dim3 gemm_grid1((N + 127) / 128, 10);
    dim3 gemm_grid2((N + 127) / 128, 9);   // layer-2 qWe needs only cols [512,528)
    const int tn = N * 128;
    const int node_blocks = (N + 15) / 16;   // 16 nodes (16 quarter-waves) per 256-thread block
    const int scan_blocks = (N + 255) / 256; // <=256 required (N<=65536)
    const int SEG = 640 * 128;
    const long prep_total = (long)tn + 2 * SEG + E;
    const int prep_all_blocks = (int)((prep_total + 255) / 256);

    // ---- fused prep: convert_x + prep_w(1) + prep_w(2) + degree ----
    hipMemsetAsync(deg, 0, (size_t)N * 4, stream);
    prep_all<<<prep_all_blocks, 256, 0, stream>>>(
        x, xb, tn, ei, deg, E,
        Wq1, bq1, Wk1, bk1, Wv1, bv1, be1, Ws1, bs1, We1, Wt1, bias1,
        Wq2, bq2, Wk2, bk2, Wv2, bv2, be2, Ws2, bs2, We2, Wt2, bias2);

    // ---- CSR build (shared by both layers) ----
    scan_part1<<<scan_blocks, 256, 0, stream>>>(deg, partial, N);
    scan_part2<<<1, 256, 0, stream>>>(partial, scan_blocks);
    scan_part3<<<scan_blocks, 256, 0, stream>>>(deg, partial, rowptr, cursor, N);
    scatter_kernel<<<(E + 255) / 256, 256, 0, stream>>>(ei, cursor, csr, E);

    // ---- layer 1 (H=8, C=16, concat) ----
    gemm_bf16<<<gemm_grid1, 256, 0, stream>>>(xb, N, Wt1, bias1, P, qWe);
    fused1_node<<<node_blocks, 256, 0, stream>>>(P, qWe, ea, We1, csr, rowptr, h1b, N);

    // ---- layer 2 (H=1, C=128, mean==identity) ----
    gemm_bf16<<<gemm_grid2, 256, 0, stream>>>(h1b, N, Wt2, bias2, P, qWe);
    fused2_node<<<node_blocks, 256, 0, stream>>>(P, qWe, ea, We2, csr, rowptr, (float*)d_out, N);
}